// Round 4
// baseline (761.327 us; speedup 1.0000x reference)
//
#include <hip/hip_runtime.h>

typedef unsigned short u16;
typedef __attribute__((ext_vector_type(8))) short s8v;   // 8 x bf16
typedef __attribute__((ext_vector_type(4))) float f4v;   // 4 x f32

#define NB 4   // batches per block (weight L2 amortization)

__device__ __forceinline__ float bf2f(u16 u) {
    union { unsigned u; float f; } c; c.u = ((unsigned)u) << 16; return c.f;
}
__device__ __forceinline__ u16 f2bf(float f) {
    union { float f; unsigned u; } c; c.f = f;
    return (u16)((c.u + 0x7FFFu + ((c.u >> 16) & 1u)) >> 16);
}
__device__ __forceinline__ f4v mfma16(s8v a, s8v b, f4v c) {
    return __builtin_amdgcn_mfma_f32_16x16x32_bf16(a, b, c, 0, 0, 0);
}

__constant__ int POOL_A[12] = {2,5,1,0,8,14,11,10, 0,2,5,4};
__constant__ int POOL_B[12] = {3,6,4,7,9,15,12,13, 1,3,6,7};

// ---- prep: pack Wcat = [Wq_h | diag(g)Wk_h | diag(g)Wv_h] per head, fragment-major.
__global__ void pack_wcat(const float* __restrict__ Wq, const float* __restrict__ Wkv,
                          const float* __restrict__ gamma, u16* __restrict__ Wfrag) {
    int blk = blockIdx.x;               // (h*12+nt)*16+kt, 1536 blocks
    int kt = blk & 15, hn = blk >> 4;
    int nt = hn % 12, h = hn / 12;
    int lane = threadIdx.x, l15 = lane & 15, quad = lane >> 4;
    int r0 = kt * 32 + quad * 8;
    s8v v;
    if (nt < 4) {
        int c = h * 64 + nt * 16 + l15;
#pragma unroll
        for (int j = 0; j < 8; ++j) v[j] = (short)f2bf(Wq[(size_t)(r0 + j) * 512 + c]);
    } else {
        int c = (nt < 8) ? (h * 64 + (nt - 4) * 16 + l15)
                         : (512 + h * 64 + (nt - 8) * 16 + l15);
#pragma unroll
        for (int j = 0; j < 8; ++j)
            v[j] = (short)f2bf(gamma[r0 + j] * Wkv[(size_t)(r0 + j) * 1024 + c]);
    }
    *(s8v*)&Wfrag[(size_t)blk * 512 + lane * 8] = v;
}

__global__ void pack_wp(const float* __restrict__ Wproj, u16* __restrict__ Wpfrag) {
    int blk = blockIdx.x;               // 512 blocks
    int n = blk & 31, hk = blk >> 5;
    int kt = hk & 1, h = hk >> 1;
    int lane = threadIdx.x, l15 = lane & 15, quad = lane >> 4;
    int r0 = h * 64 + kt * 32 + quad * 8;
    int c = n * 16 + l15;
    s8v v;
#pragma unroll
    for (int j = 0; j < 8; ++j) v[j] = (short)f2bf(Wproj[(size_t)(r0 + j) * 512 + c]);
    *(s8v*)&Wpfrag[(size_t)blk * 512 + lane * 8] = v;
}

// gkv[h*256 + s*64 + c] — parallel: 32 blocks x 256 thr, r-split + LDS reduce
__global__ void gemv_g(const float* __restrict__ Wkv, const float* __restrict__ gamma,
                       const float* __restrict__ beta, float* __restrict__ gkv) {
    __shared__ float red[256];
    int o = blockIdx.x * 64 + (threadIdx.x & 63);   // output index 0..2047
    int rc = threadIdx.x >> 6;                      // r-chunk 0..3
    int h = o >> 8, s = (o >> 6) & 3, c = o & 63;
    int col = (s < 2) ? (h * 64 + c) : (512 + h * 64 + c);
    const float* vec = (s & 1) ? beta : gamma;
    float acc = 0.f;
    for (int r = rc * 128; r < rc * 128 + 128; ++r)
        acc += vec[r] * Wkv[(size_t)r * 1024 + col];
    red[threadIdx.x] = acc;
    __syncthreads();
    if (rc == 0)
        gkv[o] = red[threadIdx.x] + red[threadIdx.x + 64] +
                 red[threadIdx.x + 128] + red[threadIdx.x + 192];
}

// ---- fused kernel: 4 batches/block, 1024 threads (16 waves), head-pipelined.
// Phase A(h): waves 0-5 GEMM(h) (2 nt-streams/wave, shared A-reads)  ||  waves 12-15 attn(h-1)
// Phase B(h): all: P3b(h) (K-part scatter-free + V-part b128-transpose) + proj(h-1);
//             attn waves preload q(h) regs.
__global__ __launch_bounds__(1024, 4) void fused_spa(
    const float* __restrict__ x,
    const u16*  __restrict__ Wfrag,
    const u16*  __restrict__ Wpfrag,
    const float* __restrict__ gkv,
    const float* __restrict__ bproj,
    float* __restrict__ out)
{
    __shared__ __align__(16) unsigned char smem[163712];
    u16*   XS   = (u16*)smem;                   // [64][520]
    float* YS   = (float*)(smem + 66560);       // [64][132]  (k cols 0..63, v cols 64..127)
    u16*   QH   = (u16*)(smem + 100352);        // [64][72]
    u16*   OS   = (u16*)(smem + 109568);        // [64][72]
    u16*   KH   = (u16*)(smem + 118784);        // [128][72]
    u16*   VT   = (u16*)(smem + 137216);        // [4][64][40]
    u16*   PB   = (u16*)(smem + 157696);        // [4][16][40]
    float* STraw   = (float*)(smem + 162816);   // [64][2] (mu, E[x^2]) -- dead after P2b
    float* STcross = (float*)(smem + 163328);   // [48]                 -- dead after P2b
    float* STfin   = (float*)(smem + 162816);   // [112][2] overlays STraw/STcross

    const int tid  = (int)threadIdx.x;
    const int w    = tid >> 6;                  // 0..15
    const int lane = tid & 63;
    const int l15  = lane & 15;
    const int quad = lane >> 4;
    const size_t grow0 = (size_t)blockIdx.x * (NB * 16);
    const int abatch = w - 12;                  // attn-wave batch (valid for w>=12)

    // P1: stage x (f32) -> XS bf16. row=tid>>4 (0..63), 32 cols each
    {
        int row = tid >> 4, col = (tid & 15) * 32;
        const float4* src = (const float4*)(x + (grow0 + row) * 512 + col);
        u16* dst = XS + row * 520 + col;
#pragma unroll
        for (int i = 0; i < 4; ++i) {
            float4 f0 = src[2 * i], f1 = src[2 * i + 1];
            s8v o;
            o[0] = (short)f2bf(f0.x); o[1] = (short)f2bf(f0.y);
            o[2] = (short)f2bf(f0.z); o[3] = (short)f2bf(f0.w);
            o[4] = (short)f2bf(f1.x); o[5] = (short)f2bf(f1.y);
            o[6] = (short)f2bf(f1.z); o[7] = (short)f2bf(f1.w);
            *(s8v*)(dst + i * 8) = o;
        }
    }
    __syncthreads();

    // P2a: per-row stats + cross dots
    {
#pragma unroll
        for (int i = 0; i < 4; ++i) {
            int row = w * 4 + i;                  // 0..63
            s8v t = *(const s8v*)&XS[row * 520 + lane * 8];
            float s = 0.f, s2 = 0.f;
#pragma unroll
            for (int j = 0; j < 8; ++j) { float v = bf2f((u16)t[j]); s += v; s2 += v * v; }
#pragma unroll
            for (int d = 1; d < 64; d <<= 1) { s += __shfl_xor(s, d); s2 += __shfl_xor(s2, d); }
            if (lane == 0) { STraw[row * 2] = s * (1.f/512.f); STraw[row * 2 + 1] = s2 * (1.f/512.f); }
        }
#pragma unroll
        for (int i = 0; i < 3; ++i) {
            int d = w * 3 + i;                    // 0..47
            int batch = d / 12, pr = d % 12;
            int ra = batch * 16 + POOL_A[pr], rb = batch * 16 + POOL_B[pr];
            s8v ta = *(const s8v*)&XS[ra * 520 + lane * 8];
            s8v tb = *(const s8v*)&XS[rb * 520 + lane * 8];
            float s = 0.f;
#pragma unroll
            for (int j = 0; j < 8; ++j) s += bf2f((u16)ta[j]) * bf2f((u16)tb[j]);
#pragma unroll
            for (int dd = 1; dd < 64; dd <<= 1) s += __shfl_xor(s, dd);
            if (lane == 0) STcross[batch * 12 + pr] = s * (1.f/512.f);
        }
    }
    __syncthreads();

    // P2b: finalize (rstd, -rstd*mu). STfin overlays -> regs, barrier, write.
    {
        float f_rstd = 0.f, f_nmu = 0.f;
        if (tid < 112) {
            int batch = tid / 28, pr = tid % 28;
            float mu, E2;
            if (pr < 16) {
                mu = STraw[(batch * 16 + pr) * 2];
                E2 = STraw[(batch * 16 + pr) * 2 + 1];
            } else {
                int j = pr - 16;
                int ra = batch * 16 + POOL_A[j], rb = batch * 16 + POOL_B[j];
                float ma = STraw[ra * 2], mb = STraw[rb * 2];
                float Ea = STraw[ra * 2 + 1], Eb = STraw[rb * 2 + 1];
                mu = 0.5f * (ma + mb);
                E2 = 0.25f * (Ea + 2.f * STcross[batch * 12 + j] + Eb);
            }
            float var = E2 - mu * mu;
            f_rstd = rsqrtf(var + 1e-5f);
            f_nmu  = -f_rstd * mu;
        }
        __syncthreads();
        if (tid < 112) { STfin[tid * 2] = f_rstd; STfin[tid * 2 + 1] = f_nmu; }
        __syncthreads();
    }

    f4v psum[8] = {};          // proj acc: tiles m=0..3 x nn=0..1 (cols n = w*2+nn)
    s8v aq0 = {}, aq1 = {};    // attn-wave q fragments (preloaded in phase B)

    for (int h = 0; h <= 8; ++h) {
        // ---------------- Phase A ----------------
        if (h < 8 && w < 6) {
            // GEMM(h): wave owns 2 nt-streams, shares each A-read across both.
            // w<4: (q_w, k_w) = nt {w, 4+w}; w=4: (v0,v1)=nt{8,9}; w=5: (v2,v3)=nt{10,11}
            int nt0 = (w < 4) ? w : (8 + (w - 4) * 2);
            int nt1 = (w < 4) ? (4 + w) : (9 + (w - 4) * 2);
            f4v acc0[4] = {}, acc1[4] = {};
            const u16* bp0 = Wfrag + ((size_t)(h * 12 + nt0) * 16) * 512 + lane * 8;
            const u16* bp1 = Wfrag + ((size_t)(h * 12 + nt1) * 16) * 512 + lane * 8;
#pragma unroll 4
            for (int kt = 0; kt < 16; ++kt) {
                s8v b0 = *(const s8v*)(bp0 + kt * 512);
                s8v b1 = *(const s8v*)(bp1 + kt * 512);
                int ka = kt * 32 + quad * 8;
#pragma unroll
                for (int m = 0; m < 4; ++m) {
                    s8v a = *(const s8v*)&XS[(m * 16 + l15) * 520 + ka];
                    acc0[m] = mfma16(a, b0, acc0[m]);
                    acc1[m] = mfma16(a, b1, acc1[m]);
                }
            }
            if (w < 4) {
#pragma unroll
                for (int m = 0; m < 4; ++m)
#pragma unroll
                    for (int r = 0; r < 4; ++r) {
                        int row = m * 16 + quad * 4 + r;
                        QH[row * 72 + w * 16 + l15] = f2bf(acc0[m][r] * 0.125f);  // q (scaled)
                        YS[row * 132 + w * 16 + l15] = acc1[m][r];                // raw Yk
                    }
            } else {
                int v0 = (w - 4) * 2;
#pragma unroll
                for (int m = 0; m < 4; ++m)
#pragma unroll
                    for (int r = 0; r < 4; ++r) {
                        int row = m * 16 + quad * 4 + r;
                        YS[row * 132 + 64 + v0 * 16 + l15]       = acc0[m][r];    // raw Yv
                        YS[row * 132 + 64 + (v0 + 1) * 16 + l15] = acc1[m][r];    // raw Yv
                    }
            }
        } else if (h >= 1 && w >= 12) {
            // Attention(h-1), batch = abatch. q in regs; K/V from (h-1) buffers.
            f4v s0 = {}, s1 = {};
            {
                s8v bk0 = *(const s8v*)&KH[(abatch * 32 + l15) * 72 + quad * 8];
                s8v bk1 = *(const s8v*)&KH[(abatch * 32 + 16 + l15) * 72 + quad * 8];
                s0 = mfma16(aq0, bk0, s0);
                s1 = mfma16(aq0, bk1, s1);
                bk0 = *(const s8v*)&KH[(abatch * 32 + l15) * 72 + 32 + quad * 8];
                bk1 = *(const s8v*)&KH[(abatch * 32 + 16 + l15) * 72 + 32 + quad * 8];
                s0 = mfma16(aq1, bk0, s0);
                s1 = mfma16(aq1, bk1, s1);
            }
            bool valid1 = (l15 < 12);
#pragma unroll
            for (int r = 0; r < 4; ++r) {
                float v0 = s0[r];
                float v1 = valid1 ? s1[r] : -1e30f;
                float mx = fmaxf(v0, v1);
#pragma unroll
                for (int d = 1; d < 16; d <<= 1) mx = fmaxf(mx, __shfl_xor(mx, d));
                float p0 = __expf(v0 - mx);
                float p1 = valid1 ? __expf(v1 - mx) : 0.f;
                float sm = p0 + p1;
#pragma unroll
                for (int d = 1; d < 16; d <<= 1) sm += __shfl_xor(sm, d);
                float inv = 1.f / sm;
                int row = quad * 4 + r;
                PB[(abatch * 16 + row) * 40 + l15]      = f2bf(p0 * inv);
                PB[(abatch * 16 + row) * 40 + 16 + l15] = f2bf(p1 * inv);
            }
            s8v ap = *(const s8v*)&PB[(abatch * 16 + l15) * 40 + quad * 8];
#pragma unroll
            for (int nt = 0; nt < 4; ++nt) {
                s8v bv = *(const s8v*)&VT[(abatch * 64 + nt * 16 + l15) * 40 + quad * 8];
                f4v o = {};
                o = mfma16(ap, bv, o);
#pragma unroll
                for (int r = 0; r < 4; ++r)
                    OS[(abatch * 16 + quad * 4 + r) * 72 + nt * 16 + l15] = f2bf(o[r]);
            }
        }
        __syncthreads();

        // ---------------- Phase B ----------------
        if (h >= 1) {
            // proj(h-1): all 16 waves, cols n = w*2 + {0,1}, K-slice = head h-1
            const int hp = h - 1;
#pragma unroll
            for (int kt = 0; kt < 2; ++kt) {
                int ka = kt * 32 + quad * 8;
                s8v a[4];
#pragma unroll
                for (int m = 0; m < 4; ++m)
                    a[m] = *(const s8v*)&OS[(m * 16 + l15) * 72 + ka];
#pragma unroll
                for (int nn = 0; nn < 2; ++nn) {
                    int n = w * 2 + nn;
                    s8v bb = *(const s8v*)&Wpfrag[((size_t)((hp * 2 + kt) * 32 + n)) * 512 + lane * 8];
#pragma unroll
                    for (int m = 0; m < 4; ++m)
                        psum[m * 2 + nn] = mfma16(a[m], bb, psum[m * 2 + nn]);
                }
            }
        }
        if (h < 8) {
            // P3b(h) K-part: form KH from raw Yk via per-row affine (b128 writes)
            {
                int rowid = tid >> 3;             // 0..127
                int c0 = (tid & 7) * 8;           // 0..56
                int batch = rowid >> 5, pr = rowid & 31;
                if (pr < 28) {
                    float alpha = STfin[(batch * 28 + pr) * 2];
                    float beta_ = STfin[(batch * 28 + pr) * 2 + 1];
                    float yk[8];
                    if (pr < 16) {
                        const float* yr = YS + (batch * 16 + pr) * 132;
#pragma unroll
                        for (int i = 0; i < 8; ++i) yk[i] = yr[c0 + i];
                    } else {
                        int j = pr - 16;
                        const float* ya = YS + (batch * 16 + POOL_A[j]) * 132;
                        const float* yb = YS + (batch * 16 + POOL_B[j]) * 132;
#pragma unroll
                        for (int i = 0; i < 8; ++i) yk[i] = 0.5f * (ya[c0 + i] + yb[c0 + i]);
                    }
                    const float* g = gkv + h * 256;
                    s8v kk;
#pragma unroll
                    for (int i = 0; i < 8; ++i)
                        kk[i] = (short)f2bf(alpha * yk[i] + beta_ * g[c0 + i] + g[64 + c0 + i]);
                    *(s8v*)&KH[(batch * 32 + pr) * 72 + c0] = kk;
                } else {
                    s8v z = {0,0,0,0,0,0,0,0};
                    *(s8v*)&KH[(batch * 32 + pr) * 72 + c0] = z;
                }
            }
            // P3b(h) V-part: wave = (batch=w>>2, chunk=w&3), lane = d. b128 VT writes,
            // banks 20*lane mod 32 -> uniform (conflict-free transpose).
            {
                int vb = w >> 2, ch = w & 3;
                int d = lane;
                const float* g = gkv + h * 256;
                float g2 = g[128 + d], g3 = g[192 + d];
                s8v vv;
#pragma unroll
                for (int i = 0; i < 8; ++i) {
                    int pr = ch * 8 + i;
                    float vf;
                    if (pr < 16) {
                        float alpha = STfin[(vb * 28 + pr) * 2];
                        float beta_ = STfin[(vb * 28 + pr) * 2 + 1];
                        float yv = YS[(vb * 16 + pr) * 132 + 64 + d];
                        vf = alpha * yv + beta_ * g2 + g3;
                    } else if (pr < 28) {
                        int j = pr - 16;
                        float alpha = STfin[(vb * 28 + pr) * 2];
                        float beta_ = STfin[(vb * 28 + pr) * 2 + 1];
                        float yv = 0.5f * (YS[(vb * 16 + POOL_A[j]) * 132 + 64 + d] +
                                           YS[(vb * 16 + POOL_B[j]) * 132 + 64 + d]);
                        vf = alpha * yv + beta_ * g2 + g3;
                    } else {
                        vf = 0.f;
                    }
                    vv[i] = (short)f2bf(vf);
                }
                *(s8v*)&VT[((size_t)vb * 64 + d) * 40 + ch * 8] = vv;
            }
            // attn waves: preload q(h) fragments (QH stable until GEMM(h+1))
            if (w >= 12) {
                aq0 = *(const s8v*)&QH[(abatch * 16 + l15) * 72 + quad * 8];
                aq1 = *(const s8v*)&QH[(abatch * 16 + l15) * 72 + 32 + quad * 8];
            }
        }
        __syncthreads();
    }

    // P4: write out (f32) + bias
#pragma unroll
    for (int nn = 0; nn < 2; ++nn) {
        int n = w * 2 + nn;
        float bias = bproj[n * 16 + l15];
#pragma unroll
        for (int m = 0; m < 4; ++m)
#pragma unroll
            for (int r = 0; r < 4; ++r)
                out[(grow0 + m * 16 + quad * 4 + r) * 512 + n * 16 + l15] =
                    psum[m * 2 + nn][r] + bias;
    }
}

extern "C" void kernel_launch(void* const* d_in, const int* in_sizes, int n_in,
                              void* d_out, int out_size, void* d_ws, size_t ws_size,
                              hipStream_t stream) {
    const float* x     = (const float*)d_in[0];
    const float* Wq    = (const float*)d_in[1];
    const float* Wkv   = (const float*)d_in[2];
    const float* Wproj = (const float*)d_in[3];
    const float* bproj = (const float*)d_in[4];
    const float* gamma = (const float*)d_in[5];
    const float* beta  = (const float*)d_in[6];
    float* out = (float*)d_out;

    u16*   Wfrag  = (u16*)d_ws;                      // 1536*512 halves = 1.5 MiB
    u16*   Wpfrag = Wfrag + (size_t)1536 * 512;      // 512*512 halves = 0.5 MiB
    float* gkv    = (float*)(Wpfrag + (size_t)512 * 512);  // 2048 f32 = 8 KiB

    pack_wcat<<<1536, 64, 0, stream>>>(Wq, Wkv, gamma, Wfrag);
    pack_wp<<<512, 64, 0, stream>>>(Wproj, Wpfrag);
    gemv_g<<<32, 256, 0, stream>>>(Wkv, gamma, beta, gkv);

    fused_spa<<<4096 / NB, 1024, 0, stream>>>(x, Wfrag, Wpfrag, gkv, bproj, out);
}

// Round 6
// 684.468 us; speedup vs baseline: 1.1123x; 1.1123x over previous
//
#include <hip/hip_runtime.h>

typedef unsigned short u16;
typedef __attribute__((ext_vector_type(8))) short s8v;   // 8 x bf16
typedef __attribute__((ext_vector_type(4))) float f4v;   // 4 x f32

#define NB 4   // batches per block (weight L2 amortization)

__device__ __forceinline__ float bf2f(u16 u) {
    union { unsigned u; float f; } c; c.u = ((unsigned)u) << 16; return c.f;
}
__device__ __forceinline__ u16 f2bf(float f) {
    union { float f; unsigned u; } c; c.f = f;
    return (u16)((c.u + 0x7FFFu + ((c.u >> 16) & 1u)) >> 16);
}
__device__ __forceinline__ f4v mfma16(s8v a, s8v b, f4v c) {
    return __builtin_amdgcn_mfma_f32_16x16x32_bf16(a, b, c, 0, 0, 0);
}

__constant__ int POOL_A[12] = {2,5,1,0,8,14,11,10, 0,2,5,4};
__constant__ int POOL_B[12] = {3,6,4,7,9,15,12,13, 1,3,6,7};

// ---- prep: pack Wcat = [Wq_h | diag(g)Wk_h | diag(g)Wv_h] per head, fragment-major.
__global__ void pack_wcat(const float* __restrict__ Wq, const float* __restrict__ Wkv,
                          const float* __restrict__ gamma, u16* __restrict__ Wfrag) {
    int blk = blockIdx.x;               // (h*12+nt)*16+kt, 1536 blocks
    int kt = blk & 15, hn = blk >> 4;
    int nt = hn % 12, h = hn / 12;
    int lane = threadIdx.x, l15 = lane & 15, quad = lane >> 4;
    int r0 = kt * 32 + quad * 8;
    s8v v;
    if (nt < 4) {
        int c = h * 64 + nt * 16 + l15;
#pragma unroll
        for (int j = 0; j < 8; ++j) v[j] = (short)f2bf(Wq[(size_t)(r0 + j) * 512 + c]);
    } else {
        int c = (nt < 8) ? (h * 64 + (nt - 4) * 16 + l15)
                         : (512 + h * 64 + (nt - 8) * 16 + l15);
#pragma unroll
        for (int j = 0; j < 8; ++j)
            v[j] = (short)f2bf(gamma[r0 + j] * Wkv[(size_t)(r0 + j) * 1024 + c]);
    }
    *(s8v*)&Wfrag[(size_t)blk * 512 + lane * 8] = v;
}

__global__ void pack_wp(const float* __restrict__ Wproj, u16* __restrict__ Wpfrag) {
    int blk = blockIdx.x;               // 512 blocks
    int n = blk & 31, hk = blk >> 5;
    int kt = hk & 1, h = hk >> 1;
    int lane = threadIdx.x, l15 = lane & 15, quad = lane >> 4;
    int r0 = h * 64 + kt * 32 + quad * 8;
    int c = n * 16 + l15;
    s8v v;
#pragma unroll
    for (int j = 0; j < 8; ++j) v[j] = (short)f2bf(Wproj[(size_t)(r0 + j) * 512 + c]);
    *(s8v*)&Wpfrag[(size_t)blk * 512 + lane * 8] = v;
}

// gkv[h*256 + s*64 + c] — parallel: 32 blocks x 256 thr, r-split + LDS reduce
__global__ void gemv_g(const float* __restrict__ Wkv, const float* __restrict__ gamma,
                       const float* __restrict__ beta, float* __restrict__ gkv) {
    __shared__ float red[256];
    int o = blockIdx.x * 64 + (threadIdx.x & 63);   // output index 0..2047
    int rc = threadIdx.x >> 6;                      // r-chunk 0..3
    int h = o >> 8, s = (o >> 6) & 3, c = o & 63;
    int col = (s < 2) ? (h * 64 + c) : (512 + h * 64 + c);
    const float* vec = (s & 1) ? beta : gamma;
    float acc = 0.f;
    for (int r = rc * 128; r < rc * 128 + 128; ++r)
        acc += vec[r] * Wkv[(size_t)r * 1024 + col];
    red[threadIdx.x] = acc;
    __syncthreads();
    if (rc == 0)
        gkv[o] = red[threadIdx.x] + red[threadIdx.x + 64] +
                 red[threadIdx.x + 128] + red[threadIdx.x + 192];
}

// ---- fused kernel: 4 batches/block, 1024 threads (16 waves), head-pipelined.
// Phase A(h): waves 0-11 GEMM(h): wave=(np=w>>1, mp=w&1), 2 nt-streams x 2 M-tiles
//             (A-read shared across 2 MFMAs, acc regs = 16)  ||  waves 12-15 attn(h-1)
// Phase B(h): all: P3b(h) (K-part + conflict-free V-transpose) + proj(h-1);
//             attn waves preload q(h) regs.
__global__ __launch_bounds__(1024, 4) void fused_spa(
    const float* __restrict__ x,
    const u16*  __restrict__ Wfrag,
    const u16*  __restrict__ Wpfrag,
    const float* __restrict__ gkv,
    const float* __restrict__ bproj,
    float* __restrict__ out)
{
    __shared__ __align__(16) unsigned char smem[163712];
    u16*   XS   = (u16*)smem;                   // [64][520]
    float* YS   = (float*)(smem + 66560);       // [64][132]  (k cols 0..63, v cols 64..127)
    u16*   QH   = (u16*)(smem + 100352);        // [64][72]
    u16*   OS   = (u16*)(smem + 109568);        // [64][72]
    u16*   KH   = (u16*)(smem + 118784);        // [128][72]
    u16*   VT   = (u16*)(smem + 137216);        // [4][64][40]
    u16*   PB   = (u16*)(smem + 157696);        // [4][16][40]
    float* STraw   = (float*)(smem + 162816);   // [64][2] (mu, E[x^2]) -- dead after P2b
    float* STcross = (float*)(smem + 163328);   // [48]                 -- dead after P2b
    float* STfin   = (float*)(smem + 162816);   // [112][2] overlays STraw/STcross

    const int tid  = (int)threadIdx.x;
    const int w    = tid >> 6;                  // 0..15
    const int lane = tid & 63;
    const int l15  = lane & 15;
    const int quad = lane >> 4;
    const size_t grow0 = (size_t)blockIdx.x * (NB * 16);
    const int abatch = w - 12;                  // attn-wave batch (valid for w>=12)

    // P1: stage x (f32) -> XS bf16. row=tid>>4 (0..63), 32 cols each
    {
        int row = tid >> 4, col = (tid & 15) * 32;
        const float4* src = (const float4*)(x + (grow0 + row) * 512 + col);
        u16* dst = XS + row * 520 + col;
#pragma unroll
        for (int i = 0; i < 4; ++i) {
            float4 f0 = src[2 * i], f1 = src[2 * i + 1];
            s8v o;
            o[0] = (short)f2bf(f0.x); o[1] = (short)f2bf(f0.y);
            o[2] = (short)f2bf(f0.z); o[3] = (short)f2bf(f0.w);
            o[4] = (short)f2bf(f1.x); o[5] = (short)f2bf(f1.y);
            o[6] = (short)f2bf(f1.z); o[7] = (short)f2bf(f1.w);
            *(s8v*)(dst + i * 8) = o;
        }
    }
    __syncthreads();

    // P2a: per-row stats + cross dots
    {
#pragma unroll
        for (int i = 0; i < 4; ++i) {
            int row = w * 4 + i;                  // 0..63
            s8v t = *(const s8v*)&XS[row * 520 + lane * 8];
            float s = 0.f, s2 = 0.f;
#pragma unroll
            for (int j = 0; j < 8; ++j) { float v = bf2f((u16)t[j]); s += v; s2 += v * v; }
#pragma unroll
            for (int d = 1; d < 64; d <<= 1) { s += __shfl_xor(s, d); s2 += __shfl_xor(s2, d); }
            if (lane == 0) { STraw[row * 2] = s * (1.f/512.f); STraw[row * 2 + 1] = s2 * (1.f/512.f); }
        }
#pragma unroll
        for (int i = 0; i < 3; ++i) {
            int d = w * 3 + i;                    // 0..47
            int batch = d / 12, pr = d % 12;
            int ra = batch * 16 + POOL_A[pr], rb = batch * 16 + POOL_B[pr];
            s8v ta = *(const s8v*)&XS[ra * 520 + lane * 8];
            s8v tb = *(const s8v*)&XS[rb * 520 + lane * 8];
            float s = 0.f;
#pragma unroll
            for (int j = 0; j < 8; ++j) s += bf2f((u16)ta[j]) * bf2f((u16)tb[j]);
#pragma unroll
            for (int dd = 1; dd < 64; dd <<= 1) s += __shfl_xor(s, dd);
            if (lane == 0) STcross[batch * 12 + pr] = s * (1.f/512.f);
        }
    }
    __syncthreads();

    // P2b: finalize (rstd, -rstd*mu). STfin overlays -> regs, barrier, write.
    {
        float f_rstd = 0.f, f_nmu = 0.f;
        if (tid < 112) {
            int batch = tid / 28, pr = tid % 28;
            float mu, E2;
            if (pr < 16) {
                mu = STraw[(batch * 16 + pr) * 2];
                E2 = STraw[(batch * 16 + pr) * 2 + 1];
            } else {
                int j = pr - 16;
                int ra = batch * 16 + POOL_A[j], rb = batch * 16 + POOL_B[j];
                float ma = STraw[ra * 2], mb = STraw[rb * 2];
                float Ea = STraw[ra * 2 + 1], Eb = STraw[rb * 2 + 1];
                mu = 0.5f * (ma + mb);
                E2 = 0.25f * (Ea + 2.f * STcross[batch * 12 + j] + Eb);
            }
            float var = E2 - mu * mu;
            f_rstd = rsqrtf(var + 1e-5f);
            f_nmu  = -f_rstd * mu;
        }
        __syncthreads();
        if (tid < 112) { STfin[tid * 2] = f_rstd; STfin[tid * 2 + 1] = f_nmu; }
        __syncthreads();
    }

    f4v psum[8] = {};          // proj acc: tiles m=0..3 x nn=0..1 (cols n = w*2+nn)
    s8v aq0 = {}, aq1 = {};    // attn-wave q fragments (preloaded in phase B)

    for (int h = 0; h <= 8; ++h) {
        // ---------------- Phase A ----------------
        if (h < 8 && w < 12) {
            // GEMM(h): wave = (np = w>>1, mp = w&1). 2 nt-streams x 2 M-tiles.
            // np<4: (q_np, k_np) = nt {np, 4+np}; np=4: v{8,9}; np=5: v{10,11}.
            // One A-read feeds 2 MFMAs; 12 waves balance 3/SIMD.
            int np = w >> 1, mp = w & 1;
            int nt0 = (np < 4) ? np : (8 + (np - 4) * 2);
            int nt1 = (np < 4) ? (4 + np) : (9 + (np - 4) * 2);
            f4v acc0[2] = {}, acc1[2] = {};
            const u16* bp0 = Wfrag + ((size_t)(h * 12 + nt0) * 16) * 512 + lane * 8;
            const u16* bp1 = Wfrag + ((size_t)(h * 12 + nt1) * 16) * 512 + lane * 8;
#pragma unroll 4
            for (int kt = 0; kt < 16; ++kt) {
                s8v b0 = *(const s8v*)(bp0 + kt * 512);
                s8v b1 = *(const s8v*)(bp1 + kt * 512);
                int ka = kt * 32 + quad * 8;
#pragma unroll
                for (int mm = 0; mm < 2; ++mm) {
                    s8v a = *(const s8v*)&XS[((mp * 2 + mm) * 16 + l15) * 520 + ka];
                    acc0[mm] = mfma16(a, b0, acc0[mm]);
                    acc1[mm] = mfma16(a, b1, acc1[mm]);
                }
            }
            if (np < 4) {
#pragma unroll
                for (int mm = 0; mm < 2; ++mm)
#pragma unroll
                    for (int r = 0; r < 4; ++r) {
                        int row = (mp * 2 + mm) * 16 + quad * 4 + r;
                        QH[row * 72 + np * 16 + l15] = f2bf(acc0[mm][r] * 0.125f);  // q (scaled)
                        YS[row * 132 + np * 16 + l15] = acc1[mm][r];                // raw Yk
                    }
            } else {
                int v0 = (np - 4) * 2;
#pragma unroll
                for (int mm = 0; mm < 2; ++mm)
#pragma unroll
                    for (int r = 0; r < 4; ++r) {
                        int row = (mp * 2 + mm) * 16 + quad * 4 + r;
                        YS[row * 132 + 64 + v0 * 16 + l15]       = acc0[mm][r];     // raw Yv
                        YS[row * 132 + 64 + (v0 + 1) * 16 + l15] = acc1[mm][r];     // raw Yv
                    }
            }
        } else if (h >= 1 && w >= 12) {
            // Attention(h-1), batch = abatch. q in regs; K/V from (h-1) buffers.
            f4v s0 = {}, s1 = {};
            {
                s8v bk0 = *(const s8v*)&KH[(abatch * 32 + l15) * 72 + quad * 8];
                s8v bk1 = *(const s8v*)&KH[(abatch * 32 + 16 + l15) * 72 + quad * 8];
                s0 = mfma16(aq0, bk0, s0);
                s1 = mfma16(aq0, bk1, s1);
                bk0 = *(const s8v*)&KH[(abatch * 32 + l15) * 72 + 32 + quad * 8];
                bk1 = *(const s8v*)&KH[(abatch * 32 + 16 + l15) * 72 + 32 + quad * 8];
                s0 = mfma16(aq1, bk0, s0);
                s1 = mfma16(aq1, bk1, s1);
            }
            bool valid1 = (l15 < 12);
#pragma unroll
            for (int r = 0; r < 4; ++r) {
                float v0 = s0[r];
                float v1 = valid1 ? s1[r] : -1e30f;
                float mx = fmaxf(v0, v1);
#pragma unroll
                for (int d = 1; d < 16; d <<= 1) mx = fmaxf(mx, __shfl_xor(mx, d));
                float p0 = __expf(v0 - mx);
                float p1 = valid1 ? __expf(v1 - mx) : 0.f;
                float sm = p0 + p1;
#pragma unroll
                for (int d = 1; d < 16; d <<= 1) sm += __shfl_xor(sm, d);
                float inv = 1.f / sm;
                int row = quad * 4 + r;
                PB[(abatch * 16 + row) * 40 + l15]      = f2bf(p0 * inv);
                PB[(abatch * 16 + row) * 40 + 16 + l15] = f2bf(p1 * inv);
            }
            s8v ap = *(const s8v*)&PB[(abatch * 16 + l15) * 40 + quad * 8];
#pragma unroll
            for (int nt = 0; nt < 4; ++nt) {
                s8v bv = *(const s8v*)&VT[(abatch * 64 + nt * 16 + l15) * 40 + quad * 8];
                f4v o = {};
                o = mfma16(ap, bv, o);
#pragma unroll
                for (int r = 0; r < 4; ++r)
                    OS[(abatch * 16 + quad * 4 + r) * 72 + nt * 16 + l15] = f2bf(o[r]);
            }
        }
        __syncthreads();

        // ---------------- Phase B ----------------
        if (h >= 1) {
            // proj(h-1): all 16 waves, cols n = w*2 + {0,1}, K-slice = head h-1
            const int hp = h - 1;
#pragma unroll
            for (int kt = 0; kt < 2; ++kt) {
                int ka = kt * 32 + quad * 8;
                s8v a[4];
#pragma unroll
                for (int m = 0; m < 4; ++m)
                    a[m] = *(const s8v*)&OS[(m * 16 + l15) * 72 + ka];
#pragma unroll
                for (int nn = 0; nn < 2; ++nn) {
                    int n = w * 2 + nn;
                    s8v bb = *(const s8v*)&Wpfrag[((size_t)((hp * 2 + kt) * 32 + n)) * 512 + lane * 8];
#pragma unroll
                    for (int m = 0; m < 4; ++m)
                        psum[m * 2 + nn] = mfma16(a[m], bb, psum[m * 2 + nn]);
                }
            }
        }
        if (h < 8) {
            // P3b(h) K-part: form KH from raw Yk via per-row affine (b128 writes)
            {
                int rowid = tid >> 3;             // 0..127
                int c0 = (tid & 7) * 8;           // 0..56
                int batch = rowid >> 5, pr = rowid & 31;
                if (pr < 28) {
                    float alpha = STfin[(batch * 28 + pr) * 2];
                    float beta_ = STfin[(batch * 28 + pr) * 2 + 1];
                    float yk[8];
                    if (pr < 16) {
                        const float* yr = YS + (batch * 16 + pr) * 132;
#pragma unroll
                        for (int i = 0; i < 8; ++i) yk[i] = yr[c0 + i];
                    } else {
                        int j = pr - 16;
                        const float* ya = YS + (batch * 16 + POOL_A[j]) * 132;
                        const float* yb = YS + (batch * 16 + POOL_B[j]) * 132;
#pragma unroll
                        for (int i = 0; i < 8; ++i) yk[i] = 0.5f * (ya[c0 + i] + yb[c0 + i]);
                    }
                    const float* g = gkv + h * 256;
                    s8v kk;
#pragma unroll
                    for (int i = 0; i < 8; ++i)
                        kk[i] = (short)f2bf(alpha * yk[i] + beta_ * g[c0 + i] + g[64 + c0 + i]);
                    *(s8v*)&KH[(batch * 32 + pr) * 72 + c0] = kk;
                } else {
                    s8v z = {0,0,0,0,0,0,0,0};
                    *(s8v*)&KH[(batch * 32 + pr) * 72 + c0] = z;
                }
            }
            // P3b(h) V-part: wave = (batch=w>>2, chunk=w&3), lane = d. b128 VT writes,
            // banks 20*lane mod 32 -> uniform (conflict-free transpose).
            {
                int vb = w >> 2, ch = w & 3;
                int d = lane;
                const float* g = gkv + h * 256;
                float g2 = g[128 + d], g3 = g[192 + d];
                s8v vv;
#pragma unroll
                for (int i = 0; i < 8; ++i) {
                    int pr = ch * 8 + i;
                    float vf;
                    if (pr < 16) {
                        float alpha = STfin[(vb * 28 + pr) * 2];
                        float beta_ = STfin[(vb * 28 + pr) * 2 + 1];
                        float yv = YS[(vb * 16 + pr) * 132 + 64 + d];
                        vf = alpha * yv + beta_ * g2 + g3;
                    } else if (pr < 28) {
                        int j = pr - 16;
                        float alpha = STfin[(vb * 28 + pr) * 2];
                        float beta_ = STfin[(vb * 28 + pr) * 2 + 1];
                        float yv = 0.5f * (YS[(vb * 16 + POOL_A[j]) * 132 + 64 + d] +
                                           YS[(vb * 16 + POOL_B[j]) * 132 + 64 + d]);
                        vf = alpha * yv + beta_ * g2 + g3;
                    } else {
                        vf = 0.f;
                    }
                    vv[i] = (short)f2bf(vf);
                }
                *(s8v*)&VT[((size_t)vb * 64 + d) * 40 + ch * 8] = vv;
            }
            // attn waves: preload q(h) fragments (QH stable until GEMM(h+1))
            if (w >= 12) {
                aq0 = *(const s8v*)&QH[(abatch * 16 + l15) * 72 + quad * 8];
                aq1 = *(const s8v*)&QH[(abatch * 16 + l15) * 72 + 32 + quad * 8];
            }
        }
        __syncthreads();
    }

    // P4: write out (f32) + bias
#pragma unroll
    for (int nn = 0; nn < 2; ++nn) {
        int n = w * 2 + nn;
        float bias = bproj[n * 16 + l15];
#pragma unroll
        for (int m = 0; m < 4; ++m)
#pragma unroll
            for (int r = 0; r < 4; ++r)
                out[(grow0 + m * 16 + quad * 4 + r) * 512 + n * 16 + l15] =
                    psum[m * 2 + nn][r] + bias;
    }
}

extern "C" void kernel_launch(void* const* d_in, const int* in_sizes, int n_in,
                              void* d_out, int out_size, void* d_ws, size_t ws_size,
                              hipStream_t stream) {
    const float* x     = (const float*)d_in[0];
    const float* Wq    = (const float*)d_in[1];
    const float* Wkv   = (const float*)d_in[2];
    const float* Wproj = (const float*)d_in[3];
    const float* bproj = (const float*)d_in[4];
    const float* gamma = (const float*)d_in[5];
    const float* beta  = (const float*)d_in[6];
    float* out = (float*)d_out;

    u16*   Wfrag  = (u16*)d_ws;                      // 1536*512 halves = 1.5 MiB
    u16*   Wpfrag = Wfrag + (size_t)1536 * 512;      // 512*512 halves = 0.5 MiB
    float* gkv    = (float*)(Wpfrag + (size_t)512 * 512);  // 2048 f32 = 8 KiB

    pack_wcat<<<1536, 64, 0, stream>>>(Wq, Wkv, gamma, Wfrag);
    pack_wp<<<512, 64, 0, stream>>>(Wproj, Wpfrag);
    gemv_g<<<32, 256, 0, stream>>>(Wkv, gamma, beta, gkv);

    fused_spa<<<4096 / NB, 1024, 0, stream>>>(x, Wfrag, Wpfrag, gkv, bproj, out);
}

// Round 9
// 683.583 us; speedup vs baseline: 1.1137x; 1.0013x over previous
//
#include <hip/hip_runtime.h>

typedef unsigned short u16;
typedef __attribute__((ext_vector_type(8))) short s8v;   // 8 x bf16
typedef __attribute__((ext_vector_type(4))) float f4v;   // 4 x f32

#define NB 4   // batches per block (weight L2 amortization)

__device__ __forceinline__ float bf2f(u16 u) {
    union { unsigned u; float f; } c; c.u = ((unsigned)u) << 16; return c.f;
}
__device__ __forceinline__ u16 f2bf(float f) {
    union { float f; unsigned u; } c; c.f = f;
    return (u16)((c.u + 0x7FFFu + ((c.u >> 16) & 1u)) >> 16);
}
__device__ __forceinline__ f4v mfma16(s8v a, s8v b, f4v c) {
    return __builtin_amdgcn_mfma_f32_16x16x32_bf16(a, b, c, 0, 0, 0);
}

__constant__ int POOL_A[12] = {2,5,1,0,8,14,11,10, 0,2,5,4};
__constant__ int POOL_B[12] = {3,6,4,7,9,15,12,13, 1,3,6,7};

// ---- prep: pack Wcat = [Wq_h | diag(g)Wk_h | diag(g)Wv_h] per head, fragment-major.
__global__ void pack_wcat(const float* __restrict__ Wq, const float* __restrict__ Wkv,
                          const float* __restrict__ gamma, u16* __restrict__ Wfrag) {
    int blk = blockIdx.x;               // (h*12+nt)*16+kt, 1536 blocks
    int kt = blk & 15, hn = blk >> 4;
    int nt = hn % 12, h = hn / 12;
    int lane = threadIdx.x, l15 = lane & 15, quad = lane >> 4;
    int r0 = kt * 32 + quad * 8;
    s8v v;
    if (nt < 4) {
        int c = h * 64 + nt * 16 + l15;
#pragma unroll
        for (int j = 0; j < 8; ++j) v[j] = (short)f2bf(Wq[(size_t)(r0 + j) * 512 + c]);
    } else {
        int c = (nt < 8) ? (h * 64 + (nt - 4) * 16 + l15)
                         : (512 + h * 64 + (nt - 8) * 16 + l15);
#pragma unroll
        for (int j = 0; j < 8; ++j)
            v[j] = (short)f2bf(gamma[r0 + j] * Wkv[(size_t)(r0 + j) * 1024 + c]);
    }
    *(s8v*)&Wfrag[(size_t)blk * 512 + lane * 8] = v;
}

__global__ void pack_wp(const float* __restrict__ Wproj, u16* __restrict__ Wpfrag) {
    int blk = blockIdx.x;               // 512 blocks
    int n = blk & 31, hk = blk >> 5;
    int kt = hk & 1, h = hk >> 1;
    int lane = threadIdx.x, l15 = lane & 15, quad = lane >> 4;
    int r0 = h * 64 + kt * 32 + quad * 8;
    int c = n * 16 + l15;
    s8v v;
#pragma unroll
    for (int j = 0; j < 8; ++j) v[j] = (short)f2bf(Wproj[(size_t)(r0 + j) * 512 + c]);
    *(s8v*)&Wpfrag[(size_t)blk * 512 + lane * 8] = v;
}

// gkv[h*256 + s*64 + c] — parallel: 32 blocks x 256 thr, r-split + LDS reduce
__global__ void gemv_g(const float* __restrict__ Wkv, const float* __restrict__ gamma,
                       const float* __restrict__ beta, float* __restrict__ gkv) {
    __shared__ float red[256];
    int o = blockIdx.x * 64 + (threadIdx.x & 63);   // output index 0..2047
    int rc = threadIdx.x >> 6;                      // r-chunk 0..3
    int h = o >> 8, s = (o >> 6) & 3, c = o & 63;
    int col = (s < 2) ? (h * 64 + c) : (512 + h * 64 + c);
    const float* vec = (s & 1) ? beta : gamma;
    float acc = 0.f;
    for (int r = rc * 128; r < rc * 128 + 128; ++r)
        acc += vec[r] * Wkv[(size_t)r * 1024 + col];
    red[threadIdx.x] = acc;
    __syncthreads();
    if (rc == 0)
        gkv[o] = red[threadIdx.x] + red[threadIdx.x + 64] +
                 red[threadIdx.x + 128] + red[threadIdx.x + 192];
}

// ---- fused kernel: 4 batches/block, 1024 threads (16 waves), head-pipelined.
// Phase A(h): waves 0-11 GEMM(h): wave=(np=w>>1, mp=w&1), 2 nt-streams x 2 M-tiles
//             (A-read shared, acc regs = 16, unroll 2 to cap B-staging at 16 regs)
//             ||  waves 12-15 attn(h-1)
// Phase B(h): all: P3b(h) (K-part + conflict-free V-transpose) + proj(h-1);
//             attn waves preload q(h) regs.
__global__ __launch_bounds__(1024, 4) void fused_spa(
    const float* __restrict__ x,
    const u16*  __restrict__ Wfrag,
    const u16*  __restrict__ Wpfrag,
    const float* __restrict__ gkv,
    const float* __restrict__ bproj,
    float* __restrict__ out)
{
    __shared__ __align__(16) unsigned char smem[163712];
    u16*   XS   = (u16*)smem;                   // [64][520]
    float* YS   = (float*)(smem + 66560);       // [64][132]  (k cols 0..63, v cols 64..127)
    u16*   QH   = (u16*)(smem + 100352);        // [64][72]
    u16*   OS   = (u16*)(smem + 109568);        // [64][72]
    u16*   KH   = (u16*)(smem + 118784);        // [128][72]
    u16*   VT   = (u16*)(smem + 137216);        // [4][64][40]
    u16*   PB   = (u16*)(smem + 157696);        // [4][16][40]
    float* STraw   = (float*)(smem + 162816);   // [64][2] (mu, E[x^2]) -- dead after P2b
    float* STcross = (float*)(smem + 163328);   // [48]                 -- dead after P2b
    float* STfin   = (float*)(smem + 162816);   // [112][2] overlays STraw/STcross

    const int tid  = (int)threadIdx.x;
    const int w    = tid >> 6;                  // 0..15
    const int lane = tid & 63;
    const int l15  = lane & 15;
    const int quad = lane >> 4;
    const size_t grow0 = (size_t)blockIdx.x * (NB * 16);
    const int abatch = w - 12;                  // attn-wave batch (valid for w>=12)

    // P1: stage x (f32) -> XS bf16. row=tid>>4 (0..63), 32 cols each
    {
        int row = tid >> 4, col = (tid & 15) * 32;
        const float4* src = (const float4*)(x + (grow0 + row) * 512 + col);
        u16* dst = XS + row * 520 + col;
#pragma unroll
        for (int i = 0; i < 4; ++i) {
            float4 f0 = src[2 * i], f1 = src[2 * i + 1];
            s8v o;
            o[0] = (short)f2bf(f0.x); o[1] = (short)f2bf(f0.y);
            o[2] = (short)f2bf(f0.z); o[3] = (short)f2bf(f0.w);
            o[4] = (short)f2bf(f1.x); o[5] = (short)f2bf(f1.y);
            o[6] = (short)f2bf(f1.z); o[7] = (short)f2bf(f1.w);
            *(s8v*)(dst + i * 8) = o;
        }
    }
    __syncthreads();

    // P2a: per-row stats + cross dots
    {
#pragma unroll
        for (int i = 0; i < 4; ++i) {
            int row = w * 4 + i;                  // 0..63
            s8v t = *(const s8v*)&XS[row * 520 + lane * 8];
            float s = 0.f, s2 = 0.f;
#pragma unroll
            for (int j = 0; j < 8; ++j) { float v = bf2f((u16)t[j]); s += v; s2 += v * v; }
#pragma unroll
            for (int d = 1; d < 64; d <<= 1) { s += __shfl_xor(s, d); s2 += __shfl_xor(s2, d); }
            if (lane == 0) { STraw[row * 2] = s * (1.f/512.f); STraw[row * 2 + 1] = s2 * (1.f/512.f); }
        }
#pragma unroll
        for (int i = 0; i < 3; ++i) {
            int d = w * 3 + i;                    // 0..47
            int batch = d / 12, pr = d % 12;
            int ra = batch * 16 + POOL_A[pr], rb = batch * 16 + POOL_B[pr];
            s8v ta = *(const s8v*)&XS[ra * 520 + lane * 8];
            s8v tb = *(const s8v*)&XS[rb * 520 + lane * 8];
            float s = 0.f;
#pragma unroll
            for (int j = 0; j < 8; ++j) s += bf2f((u16)ta[j]) * bf2f((u16)tb[j]);
#pragma unroll
            for (int dd = 1; dd < 64; dd <<= 1) s += __shfl_xor(s, dd);
            if (lane == 0) STcross[batch * 12 + pr] = s * (1.f/512.f);
        }
    }
    __syncthreads();

    // P2b: finalize (rstd, -rstd*mu). STfin overlays -> regs, barrier, write.
    {
        float f_rstd = 0.f, f_nmu = 0.f;
        if (tid < 112) {
            int batch = tid / 28, pr = tid % 28;
            float mu, E2;
            if (pr < 16) {
                mu = STraw[(batch * 16 + pr) * 2];
                E2 = STraw[(batch * 16 + pr) * 2 + 1];
            } else {
                int j = pr - 16;
                int ra = batch * 16 + POOL_A[j], rb = batch * 16 + POOL_B[j];
                float ma = STraw[ra * 2], mb = STraw[rb * 2];
                float Ea = STraw[ra * 2 + 1], Eb = STraw[rb * 2 + 1];
                mu = 0.5f * (ma + mb);
                E2 = 0.25f * (Ea + 2.f * STcross[batch * 12 + j] + Eb);
            }
            float var = E2 - mu * mu;
            f_rstd = rsqrtf(var + 1e-5f);
            f_nmu  = -f_rstd * mu;
        }
        __syncthreads();
        if (tid < 112) { STfin[tid * 2] = f_rstd; STfin[tid * 2 + 1] = f_nmu; }
        __syncthreads();
    }

    f4v psum[8] = {};          // proj acc: tiles m=0..3 x nn=0..1 (cols n = w*2+nn)
    s8v aq0 = {}, aq1 = {};    // attn-wave q fragments (preloaded in phase B)

    for (int h = 0; h <= 8; ++h) {
        // ---------------- Phase A ----------------
        if (h < 8 && w < 12) {
            // GEMM(h): wave = (np = w>>1, mp = w&1). 2 nt-streams x 2 M-tiles.
            // np<4: (q_np, k_np) = nt {np, 4+np}; np=4: v{8,9}; np=5: v{10,11}.
            // One A-read feeds 2 MFMAs; unroll 2 keeps B-staging at 16 regs (no spill).
            int np = w >> 1, mp = w & 1;
            int nt0 = (np < 4) ? np : (8 + (np - 4) * 2);
            int nt1 = (np < 4) ? (4 + np) : (9 + (np - 4) * 2);
            f4v acc0[2] = {}, acc1[2] = {};
            const u16* bp0 = Wfrag + ((size_t)(h * 12 + nt0) * 16) * 512 + lane * 8;
            const u16* bp1 = Wfrag + ((size_t)(h * 12 + nt1) * 16) * 512 + lane * 8;
#pragma unroll 2
            for (int kt = 0; kt < 16; ++kt) {
                s8v b0 = *(const s8v*)(bp0 + kt * 512);
                s8v b1 = *(const s8v*)(bp1 + kt * 512);
                int ka = kt * 32 + quad * 8;
#pragma unroll
                for (int mm = 0; mm < 2; ++mm) {
                    s8v a = *(const s8v*)&XS[((mp * 2 + mm) * 16 + l15) * 520 + ka];
                    acc0[mm] = mfma16(a, b0, acc0[mm]);
                    acc1[mm] = mfma16(a, b1, acc1[mm]);
                }
            }
            if (np < 4) {
#pragma unroll
                for (int mm = 0; mm < 2; ++mm)
#pragma unroll
                    for (int r = 0; r < 4; ++r) {
                        int row = (mp * 2 + mm) * 16 + quad * 4 + r;
                        QH[row * 72 + np * 16 + l15] = f2bf(acc0[mm][r] * 0.125f);  // q (scaled)
                        YS[row * 132 + np * 16 + l15] = acc1[mm][r];                // raw Yk
                    }
            } else {
                int v0 = (np - 4) * 2;
#pragma unroll
                for (int mm = 0; mm < 2; ++mm)
#pragma unroll
                    for (int r = 0; r < 4; ++r) {
                        int row = (mp * 2 + mm) * 16 + quad * 4 + r;
                        YS[row * 132 + 64 + v0 * 16 + l15]       = acc0[mm][r];     // raw Yv
                        YS[row * 132 + 64 + (v0 + 1) * 16 + l15] = acc1[mm][r];     // raw Yv
                    }
            }
        } else if (h >= 1 && w >= 12) {
            // Attention(h-1), batch = abatch. q in regs; K/V from (h-1) buffers.
            f4v s0 = {}, s1 = {};
            {
                s8v bk0 = *(const s8v*)&KH[(abatch * 32 + l15) * 72 + quad * 8];
                s8v bk1 = *(const s8v*)&KH[(abatch * 32 + 16 + l15) * 72 + quad * 8];
                s0 = mfma16(aq0, bk0, s0);
                s1 = mfma16(aq0, bk1, s1);
                bk0 = *(const s8v*)&KH[(abatch * 32 + l15) * 72 + 32 + quad * 8];
                bk1 = *(const s8v*)&KH[(abatch * 32 + 16 + l15) * 72 + 32 + quad * 8];
                s0 = mfma16(aq1, bk0, s0);
                s1 = mfma16(aq1, bk1, s1);
            }
            bool valid1 = (l15 < 12);
#pragma unroll
            for (int r = 0; r < 4; ++r) {
                float v0 = s0[r];
                float v1 = valid1 ? s1[r] : -1e30f;
                float mx = fmaxf(v0, v1);
#pragma unroll
                for (int d = 1; d < 16; d <<= 1) mx = fmaxf(mx, __shfl_xor(mx, d));
                float p0 = __expf(v0 - mx);
                float p1 = valid1 ? __expf(v1 - mx) : 0.f;
                float sm = p0 + p1;
#pragma unroll
                for (int d = 1; d < 16; d <<= 1) sm += __shfl_xor(sm, d);
                float inv = 1.f / sm;
                int row = quad * 4 + r;
                PB[(abatch * 16 + row) * 40 + l15]      = f2bf(p0 * inv);
                PB[(abatch * 16 + row) * 40 + 16 + l15] = f2bf(p1 * inv);
            }
            s8v ap = *(const s8v*)&PB[(abatch * 16 + l15) * 40 + quad * 8];
#pragma unroll
            for (int nt = 0; nt < 4; ++nt) {
                s8v bv = *(const s8v*)&VT[(abatch * 64 + nt * 16 + l15) * 40 + quad * 8];
                f4v o = {};
                o = mfma16(ap, bv, o);
#pragma unroll
                for (int r = 0; r < 4; ++r)
                    OS[(abatch * 16 + quad * 4 + r) * 72 + nt * 16 + l15] = f2bf(o[r]);
            }
        }
        __syncthreads();

        // ---------------- Phase B ----------------
        if (h >= 1) {
            // proj(h-1): all 16 waves, cols n = w*2 + {0,1}, K-slice = head h-1
            const int hp = h - 1;
#pragma unroll
            for (int kt = 0; kt < 2; ++kt) {
                int ka = kt * 32 + quad * 8;
                s8v a[4];
#pragma unroll
                for (int m = 0; m < 4; ++m)
                    a[m] = *(const s8v*)&OS[(m * 16 + l15) * 72 + ka];
#pragma unroll
                for (int nn = 0; nn < 2; ++nn) {
                    int n = w * 2 + nn;
                    s8v bb = *(const s8v*)&Wpfrag[((size_t)((hp * 2 + kt) * 32 + n)) * 512 + lane * 8];
#pragma unroll
                    for (int m = 0; m < 4; ++m)
                        psum[m * 2 + nn] = mfma16(a[m], bb, psum[m * 2 + nn]);
                }
            }
        }
        if (h < 8) {
            // P3b(h) K-part: form KH from raw Yk via per-row affine (b128 writes)
            {
                int rowid = tid >> 3;             // 0..127
                int c0 = (tid & 7) * 8;           // 0..56
                int batch = rowid >> 5, pr = rowid & 31;
                if (pr < 28) {
                    float alpha = STfin[(batch * 28 + pr) * 2];
                    float beta_ = STfin[(batch * 28 + pr) * 2 + 1];
                    float yk[8];
                    if (pr < 16) {
                        const float* yr = YS + (batch * 16 + pr) * 132;
#pragma unroll
                        for (int i = 0; i < 8; ++i) yk[i] = yr[c0 + i];
                    } else {
                        int j = pr - 16;
                        const float* ya = YS + (batch * 16 + POOL_A[j]) * 132;
                        const float* yb = YS + (batch * 16 + POOL_B[j]) * 132;
#pragma unroll
                        for (int i = 0; i < 8; ++i) yk[i] = 0.5f * (ya[c0 + i] + yb[c0 + i]);
                    }
                    const float* g = gkv + h * 256;
                    s8v kk;
#pragma unroll
                    for (int i = 0; i < 8; ++i)
                        kk[i] = (short)f2bf(alpha * yk[i] + beta_ * g[c0 + i] + g[64 + c0 + i]);
                    *(s8v*)&KH[(batch * 32 + pr) * 72 + c0] = kk;
                } else {
                    s8v z = {0,0,0,0,0,0,0,0};
                    *(s8v*)&KH[(batch * 32 + pr) * 72 + c0] = z;
                }
            }
            // P3b(h) V-part: wave = (batch=w>>2, chunk=w&3), lane = d. b128 VT writes,
            // banks 20*lane mod 32 -> uniform (conflict-free transpose).
            {
                int vb = w >> 2, ch = w & 3;
                int d = lane;
                const float* g = gkv + h * 256;
                float g2 = g[128 + d], g3 = g[192 + d];
                s8v vv;
#pragma unroll
                for (int i = 0; i < 8; ++i) {
                    int pr = ch * 8 + i;
                    float vf;
                    if (pr < 16) {
                        float alpha = STfin[(vb * 28 + pr) * 2];
                        float beta_ = STfin[(vb * 28 + pr) * 2 + 1];
                        float yv = YS[(vb * 16 + pr) * 132 + 64 + d];
                        vf = alpha * yv + beta_ * g2 + g3;
                    } else if (pr < 28) {
                        int j = pr - 16;
                        float alpha = STfin[(vb * 28 + pr) * 2];
                        float beta_ = STfin[(vb * 28 + pr) * 2 + 1];
                        float yv = 0.5f * (YS[(vb * 16 + POOL_A[j]) * 132 + 64 + d] +
                                           YS[(vb * 16 + POOL_B[j]) * 132 + 64 + d]);
                        vf = alpha * yv + beta_ * g2 + g3;
                    } else {
                        vf = 0.f;
                    }
                    vv[i] = (short)f2bf(vf);
                }
                *(s8v*)&VT[((size_t)vb * 64 + d) * 40 + ch * 8] = vv;
            }
            // attn waves: preload q(h) fragments (QH stable until GEMM(h+1))
            if (w >= 12) {
                aq0 = *(const s8v*)&QH[(abatch * 16 + l15) * 72 + quad * 8];
                aq1 = *(const s8v*)&QH[(abatch * 16 + l15) * 72 + 32 + quad * 8];
            }
        }
        __syncthreads();
    }

    // P4: write out (f32) + bias
#pragma unroll
    for (int nn = 0; nn < 2; ++nn) {
        int n = w * 2 + nn;
        float bias = bproj[n * 16 + l15];
#pragma unroll
        for (int m = 0; m < 4; ++m)
#pragma unroll
            for (int r = 0; r < 4; ++r)
                out[(grow0 + m * 16 + quad * 4 + r) * 512 + n * 16 + l15] =
                    psum[m * 2 + nn][r] + bias;
    }
}

extern "C" void kernel_launch(void* const* d_in, const int* in_sizes, int n_in,
                              void* d_out, int out_size, void* d_ws, size_t ws_size,
                              hipStream_t stream) {
    const float* x     = (const float*)d_in[0];
    const float* Wq    = (const float*)d_in[1];
    const float* Wkv   = (const float*)d_in[2];
    const float* Wproj = (const float*)d_in[3];
    const float* bproj = (const float*)d_in[4];
    const float* gamma = (const float*)d_in[5];
    const float* beta  = (const float*)d_in[6];
    float* out = (float*)d_out;

    u16*   Wfrag  = (u16*)d_ws;                      // 1536*512 halves = 1.5 MiB
    u16*   Wpfrag = Wfrag + (size_t)1536 * 512;      // 512*512 halves = 0.5 MiB
    float* gkv    = (float*)(Wpfrag + (size_t)512 * 512);  // 2048 f32 = 8 KiB

    pack_wcat<<<1536, 64, 0, stream>>>(Wq, Wkv, gamma, Wfrag);
    pack_wp<<<512, 64, 0, stream>>>(Wproj, Wpfrag);
    gemv_g<<<32, 256, 0, stream>>>(Wkv, gamma, beta, gkv);

    fused_spa<<<4096 / NB, 1024, 0, stream>>>(x, Wfrag, Wpfrag, gkv, bproj, out);
}

// Round 10
// 682.188 us; speedup vs baseline: 1.1160x; 1.0020x over previous
//
#include <hip/hip_runtime.h>

typedef unsigned short u16;
typedef __attribute__((ext_vector_type(8))) short s8v;   // 8 x bf16
typedef __attribute__((ext_vector_type(4))) float f4v;   // 4 x f32

#define NB 4   // batches per block (weight L2 amortization)

__device__ __forceinline__ float bf2f(u16 u) {
    union { unsigned u; float f; } c; c.u = ((unsigned)u) << 16; return c.f;
}
__device__ __forceinline__ u16 f2bf(float f) {
    union { float f; unsigned u; } c; c.f = f;
    return (u16)((c.u + 0x7FFFu + ((c.u >> 16) & 1u)) >> 16);
}
__device__ __forceinline__ f4v mfma16(s8v a, s8v b, f4v c) {
    return __builtin_amdgcn_mfma_f32_16x16x32_bf16(a, b, c, 0, 0, 0);
}

__constant__ int POOL_A[12] = {2,5,1,0,8,14,11,10, 0,2,5,4};
__constant__ int POOL_B[12] = {3,6,4,7,9,15,12,13, 1,3,6,7};

// ---- prep: pack Wcat = [Wq_h | diag(g)Wk_h | diag(g)Wv_h] per head, fragment-major.
__global__ void pack_wcat(const float* __restrict__ Wq, const float* __restrict__ Wkv,
                          const float* __restrict__ gamma, u16* __restrict__ Wfrag) {
    int blk = blockIdx.x;               // (h*12+nt)*16+kt, 1536 blocks
    int kt = blk & 15, hn = blk >> 4;
    int nt = hn % 12, h = hn / 12;
    int lane = threadIdx.x, l15 = lane & 15, quad = lane >> 4;
    int r0 = kt * 32 + quad * 8;
    s8v v;
    if (nt < 4) {
        int c = h * 64 + nt * 16 + l15;
#pragma unroll
        for (int j = 0; j < 8; ++j) v[j] = (short)f2bf(Wq[(size_t)(r0 + j) * 512 + c]);
    } else {
        int c = (nt < 8) ? (h * 64 + (nt - 4) * 16 + l15)
                         : (512 + h * 64 + (nt - 8) * 16 + l15);
#pragma unroll
        for (int j = 0; j < 8; ++j)
            v[j] = (short)f2bf(gamma[r0 + j] * Wkv[(size_t)(r0 + j) * 1024 + c]);
    }
    *(s8v*)&Wfrag[(size_t)blk * 512 + lane * 8] = v;
}

__global__ void pack_wp(const float* __restrict__ Wproj, u16* __restrict__ Wpfrag) {
    int blk = blockIdx.x;               // 512 blocks
    int n = blk & 31, hk = blk >> 5;
    int kt = hk & 1, h = hk >> 1;
    int lane = threadIdx.x, l15 = lane & 15, quad = lane >> 4;
    int r0 = h * 64 + kt * 32 + quad * 8;
    int c = n * 16 + l15;
    s8v v;
#pragma unroll
    for (int j = 0; j < 8; ++j) v[j] = (short)f2bf(Wproj[(size_t)(r0 + j) * 512 + c]);
    *(s8v*)&Wpfrag[(size_t)blk * 512 + lane * 8] = v;
}

// gkv[h*256 + s*64 + c] — parallel: 32 blocks x 256 thr, r-split + LDS reduce
__global__ void gemv_g(const float* __restrict__ Wkv, const float* __restrict__ gamma,
                       const float* __restrict__ beta, float* __restrict__ gkv) {
    __shared__ float red[256];
    int o = blockIdx.x * 64 + (threadIdx.x & 63);   // output index 0..2047
    int rc = threadIdx.x >> 6;                      // r-chunk 0..3
    int h = o >> 8, s = (o >> 6) & 3, c = o & 63;
    int col = (s < 2) ? (h * 64 + c) : (512 + h * 64 + c);
    const float* vec = (s & 1) ? beta : gamma;
    float acc = 0.f;
    for (int r = rc * 128; r < rc * 128 + 128; ++r)
        acc += vec[r] * Wkv[(size_t)r * 1024 + col];
    red[threadIdx.x] = acc;
    __syncthreads();
    if (rc == 0)
        gkv[o] = red[threadIdx.x] + red[threadIdx.x + 64] +
                 red[threadIdx.x + 128] + red[threadIdx.x + 192];
}

// ---- fused kernel: 4 batches/block, 1024 threads (16 waves), head-pipelined.
// Phase A(h): waves 0-11 GEMM(h): wave = nt, 4 M-tiles, acc[4]=16 regs (round-2
//             structure, measured spill-free)  ||  waves 12-15 attn(h-1)
// Phase B(h): all: P3b(h) (K-part + conflict-free b128 V-transpose) + proj(h-1);
//             attn waves preload q(h) regs.
__global__ __launch_bounds__(1024, 4) void fused_spa(
    const float* __restrict__ x,
    const u16*  __restrict__ Wfrag,
    const u16*  __restrict__ Wpfrag,
    const float* __restrict__ gkv,
    const float* __restrict__ bproj,
    float* __restrict__ out)
{
    __shared__ __align__(16) unsigned char smem[163712];
    u16*   XS   = (u16*)smem;                   // [64][520]
    float* YS   = (float*)(smem + 66560);       // [64][132]  (k cols 0..63, v cols 64..127)
    u16*   QH   = (u16*)(smem + 100352);        // [64][72]
    u16*   OS   = (u16*)(smem + 109568);        // [64][72]
    u16*   KH   = (u16*)(smem + 118784);        // [128][72]
    u16*   VT   = (u16*)(smem + 137216);        // [4][64][40]
    u16*   PB   = (u16*)(smem + 157696);        // [4][16][40]
    float* STraw   = (float*)(smem + 162816);   // [64][2] (mu, E[x^2]) -- dead after P2b
    float* STcross = (float*)(smem + 163328);   // [48]                 -- dead after P2b
    float* STfin   = (float*)(smem + 162816);   // [112][2] overlays STraw/STcross

    const int tid  = (int)threadIdx.x;
    const int w    = tid >> 6;                  // 0..15
    const int lane = tid & 63;
    const int l15  = lane & 15;
    const int quad = lane >> 4;
    const size_t grow0 = (size_t)blockIdx.x * (NB * 16);
    const int abatch = w - 12;                  // attn-wave batch (valid for w>=12)

    // P1: stage x (f32) -> XS bf16. row=tid>>4 (0..63), 32 cols each
    {
        int row = tid >> 4, col = (tid & 15) * 32;
        const float4* src = (const float4*)(x + (grow0 + row) * 512 + col);
        u16* dst = XS + row * 520 + col;
#pragma unroll
        for (int i = 0; i < 4; ++i) {
            float4 f0 = src[2 * i], f1 = src[2 * i + 1];
            s8v o;
            o[0] = (short)f2bf(f0.x); o[1] = (short)f2bf(f0.y);
            o[2] = (short)f2bf(f0.z); o[3] = (short)f2bf(f0.w);
            o[4] = (short)f2bf(f1.x); o[5] = (short)f2bf(f1.y);
            o[6] = (short)f2bf(f1.z); o[7] = (short)f2bf(f1.w);
            *(s8v*)(dst + i * 8) = o;
        }
    }
    __syncthreads();

    // P2a: per-row stats + cross dots
    {
#pragma unroll
        for (int i = 0; i < 4; ++i) {
            int row = w * 4 + i;                  // 0..63
            s8v t = *(const s8v*)&XS[row * 520 + lane * 8];
            float s = 0.f, s2 = 0.f;
#pragma unroll
            for (int j = 0; j < 8; ++j) { float v = bf2f((u16)t[j]); s += v; s2 += v * v; }
#pragma unroll
            for (int d = 1; d < 64; d <<= 1) { s += __shfl_xor(s, d); s2 += __shfl_xor(s2, d); }
            if (lane == 0) { STraw[row * 2] = s * (1.f/512.f); STraw[row * 2 + 1] = s2 * (1.f/512.f); }
        }
#pragma unroll
        for (int i = 0; i < 3; ++i) {
            int d = w * 3 + i;                    // 0..47
            int batch = d / 12, pr = d % 12;
            int ra = batch * 16 + POOL_A[pr], rb = batch * 16 + POOL_B[pr];
            s8v ta = *(const s8v*)&XS[ra * 520 + lane * 8];
            s8v tb = *(const s8v*)&XS[rb * 520 + lane * 8];
            float s = 0.f;
#pragma unroll
            for (int j = 0; j < 8; ++j) s += bf2f((u16)ta[j]) * bf2f((u16)tb[j]);
#pragma unroll
            for (int dd = 1; dd < 64; dd <<= 1) s += __shfl_xor(s, dd);
            if (lane == 0) STcross[batch * 12 + pr] = s * (1.f/512.f);
        }
    }
    __syncthreads();

    // P2b: finalize (rstd, -rstd*mu). STfin overlays -> regs, barrier, write.
    {
        float f_rstd = 0.f, f_nmu = 0.f;
        if (tid < 112) {
            int batch = tid / 28, pr = tid % 28;
            float mu, E2;
            if (pr < 16) {
                mu = STraw[(batch * 16 + pr) * 2];
                E2 = STraw[(batch * 16 + pr) * 2 + 1];
            } else {
                int j = pr - 16;
                int ra = batch * 16 + POOL_A[j], rb = batch * 16 + POOL_B[j];
                float ma = STraw[ra * 2], mb = STraw[rb * 2];
                float Ea = STraw[ra * 2 + 1], Eb = STraw[rb * 2 + 1];
                mu = 0.5f * (ma + mb);
                E2 = 0.25f * (Ea + 2.f * STcross[batch * 12 + j] + Eb);
            }
            float var = E2 - mu * mu;
            f_rstd = rsqrtf(var + 1e-5f);
            f_nmu  = -f_rstd * mu;
        }
        __syncthreads();
        if (tid < 112) { STfin[tid * 2] = f_rstd; STfin[tid * 2 + 1] = f_nmu; }
        __syncthreads();
    }

    f4v psum[8] = {};          // proj acc: tiles m=0..3 x nn=0..1 (cols n = w*2+nn)
    s8v aq0 = {}, aq1 = {};    // attn-wave q fragments (preloaded in phase B)

    for (int h = 0; h <= 8; ++h) {
        // ---------------- Phase A ----------------
        if (h < 8 && w < 12) {
            // GEMM(h): wave = nt = w, 4 M-tiles each (round-2 structure: acc[4],
            // single B-stream 8-reg staging -> no spill; measured 396us baseline).
            f4v acc[4] = {};
            const u16* bp = Wfrag + ((size_t)(h * 12 + w) * 16) * 512 + lane * 8;
            for (int kt = 0; kt < 16; ++kt) {
                s8v bb = *(const s8v*)(bp + kt * 512);
                int ka = kt * 32 + quad * 8;
#pragma unroll
                for (int m = 0; m < 4; ++m) {
                    s8v a = *(const s8v*)&XS[(m * 16 + l15) * 520 + ka];
                    acc[m] = mfma16(a, bb, acc[m]);
                }
            }
            if (w < 4) {            // q (scaled by 1/8)
#pragma unroll
                for (int m = 0; m < 4; ++m)
#pragma unroll
                    for (int r = 0; r < 4; ++r)
                        QH[(m * 16 + quad * 4 + r) * 72 + w * 16 + l15] = f2bf(acc[m][r] * 0.125f);
            } else if (w < 8) {     // raw Yk (f32)
#pragma unroll
                for (int m = 0; m < 4; ++m)
#pragma unroll
                    for (int r = 0; r < 4; ++r)
                        YS[(m * 16 + quad * 4 + r) * 132 + (w - 4) * 16 + l15] = acc[m][r];
            } else {                // raw Yv (f32)
#pragma unroll
                for (int m = 0; m < 4; ++m)
#pragma unroll
                    for (int r = 0; r < 4; ++r)
                        YS[(m * 16 + quad * 4 + r) * 132 + 64 + (w - 8) * 16 + l15] = acc[m][r];
            }
        } else if (h >= 1 && w >= 12) {
            // Attention(h-1), batch = abatch. q in regs; K/V from (h-1) buffers.
            f4v s0 = {}, s1 = {};
            {
                s8v bk0 = *(const s8v*)&KH[(abatch * 32 + l15) * 72 + quad * 8];
                s8v bk1 = *(const s8v*)&KH[(abatch * 32 + 16 + l15) * 72 + quad * 8];
                s0 = mfma16(aq0, bk0, s0);
                s1 = mfma16(aq0, bk1, s1);
                bk0 = *(const s8v*)&KH[(abatch * 32 + l15) * 72 + 32 + quad * 8];
                bk1 = *(const s8v*)&KH[(abatch * 32 + 16 + l15) * 72 + 32 + quad * 8];
                s0 = mfma16(aq1, bk0, s0);
                s1 = mfma16(aq1, bk1, s1);
            }
            bool valid1 = (l15 < 12);
#pragma unroll
            for (int r = 0; r < 4; ++r) {
                float v0 = s0[r];
                float v1 = valid1 ? s1[r] : -1e30f;
                float mx = fmaxf(v0, v1);
#pragma unroll
                for (int d = 1; d < 16; d <<= 1) mx = fmaxf(mx, __shfl_xor(mx, d));
                float p0 = __expf(v0 - mx);
                float p1 = valid1 ? __expf(v1 - mx) : 0.f;
                float sm = p0 + p1;
#pragma unroll
                for (int d = 1; d < 16; d <<= 1) sm += __shfl_xor(sm, d);
                float inv = 1.f / sm;
                int row = quad * 4 + r;
                PB[(abatch * 16 + row) * 40 + l15]      = f2bf(p0 * inv);
                PB[(abatch * 16 + row) * 40 + 16 + l15] = f2bf(p1 * inv);
            }
            s8v ap = *(const s8v*)&PB[(abatch * 16 + l15) * 40 + quad * 8];
#pragma unroll
            for (int nt = 0; nt < 4; ++nt) {
                s8v bv = *(const s8v*)&VT[(abatch * 64 + nt * 16 + l15) * 40 + quad * 8];
                f4v o = {};
                o = mfma16(ap, bv, o);
#pragma unroll
                for (int r = 0; r < 4; ++r)
                    OS[(abatch * 16 + quad * 4 + r) * 72 + nt * 16 + l15] = f2bf(o[r]);
            }
        }
        __syncthreads();

        // ---------------- Phase B ----------------
        if (h >= 1) {
            // proj(h-1): all 16 waves, cols n = w*2 + {0,1}, K-slice = head h-1
            const int hp = h - 1;
#pragma unroll
            for (int kt = 0; kt < 2; ++kt) {
                int ka = kt * 32 + quad * 8;
                s8v a[4];
#pragma unroll
                for (int m = 0; m < 4; ++m)
                    a[m] = *(const s8v*)&OS[(m * 16 + l15) * 72 + ka];
#pragma unroll
                for (int nn = 0; nn < 2; ++nn) {
                    int n = w * 2 + nn;
                    s8v bb = *(const s8v*)&Wpfrag[((size_t)((hp * 2 + kt) * 32 + n)) * 512 + lane * 8];
#pragma unroll
                    for (int m = 0; m < 4; ++m)
                        psum[m * 2 + nn] = mfma16(a[m], bb, psum[m * 2 + nn]);
                }
            }
        }
        if (h < 8) {
            // P3b(h) K-part: form KH from raw Yk via per-row affine (b128 writes)
            {
                int rowid = tid >> 3;             // 0..127
                int c0 = (tid & 7) * 8;           // 0..56
                int batch = rowid >> 5, pr = rowid & 31;
                if (pr < 28) {
                    float alpha = STfin[(batch * 28 + pr) * 2];
                    float beta_ = STfin[(batch * 28 + pr) * 2 + 1];
                    float yk[8];
                    if (pr < 16) {
                        const float* yr = YS + (batch * 16 + pr) * 132;
#pragma unroll
                        for (int i = 0; i < 8; ++i) yk[i] = yr[c0 + i];
                    } else {
                        int j = pr - 16;
                        const float* ya = YS + (batch * 16 + POOL_A[j]) * 132;
                        const float* yb = YS + (batch * 16 + POOL_B[j]) * 132;
#pragma unroll
                        for (int i = 0; i < 8; ++i) yk[i] = 0.5f * (ya[c0 + i] + yb[c0 + i]);
                    }
                    const float* g = gkv + h * 256;
                    s8v kk;
#pragma unroll
                    for (int i = 0; i < 8; ++i)
                        kk[i] = (short)f2bf(alpha * yk[i] + beta_ * g[c0 + i] + g[64 + c0 + i]);
                    *(s8v*)&KH[(batch * 32 + pr) * 72 + c0] = kk;
                } else {
                    s8v z = {0,0,0,0,0,0,0,0};
                    *(s8v*)&KH[(batch * 32 + pr) * 72 + c0] = z;
                }
            }
            // P3b(h) V-part: wave = (batch=w>>2, chunk=w&3), lane = d. b128 VT writes,
            // banks 20*lane mod 32 -> uniform (conflict-free transpose).
            {
                int vb = w >> 2, ch = w & 3;
                int d = lane;
                const float* g = gkv + h * 256;
                float g2 = g[128 + d], g3 = g[192 + d];
                s8v vv;
#pragma unroll
                for (int i = 0; i < 8; ++i) {
                    int pr = ch * 8 + i;
                    float vf;
                    if (pr < 16) {
                        float alpha = STfin[(vb * 28 + pr) * 2];
                        float beta_ = STfin[(vb * 28 + pr) * 2 + 1];
                        float yv = YS[(vb * 16 + pr) * 132 + 64 + d];
                        vf = alpha * yv + beta_ * g2 + g3;
                    } else if (pr < 28) {
                        int j = pr - 16;
                        float alpha = STfin[(vb * 28 + pr) * 2];
                        float beta_ = STfin[(vb * 28 + pr) * 2 + 1];
                        float yv = 0.5f * (YS[(vb * 16 + POOL_A[j]) * 132 + 64 + d] +
                                           YS[(vb * 16 + POOL_B[j]) * 132 + 64 + d]);
                        vf = alpha * yv + beta_ * g2 + g3;
                    } else {
                        vf = 0.f;
                    }
                    vv[i] = (short)f2bf(vf);
                }
                *(s8v*)&VT[((size_t)vb * 64 + d) * 40 + ch * 8] = vv;
            }
            // attn waves: preload q(h) fragments (QH stable until GEMM(h+1))
            if (w >= 12) {
                aq0 = *(const s8v*)&QH[(abatch * 16 + l15) * 72 + quad * 8];
                aq1 = *(const s8v*)&QH[(abatch * 16 + l15) * 72 + 32 + quad * 8];
            }
        }
        __syncthreads();
    }

    // P4: write out (f32) + bias
#pragma unroll
    for (int nn = 0; nn < 2; ++nn) {
        int n = w * 2 + nn;
        float bias = bproj[n * 16 + l15];
#pragma unroll
        for (int m = 0; m < 4; ++m)
#pragma unroll
            for (int r = 0; r < 4; ++r)
                out[(grow0 + m * 16 + quad * 4 + r) * 512 + n * 16 + l15] =
                    psum[m * 2 + nn][r] + bias;
    }
}

extern "C" void kernel_launch(void* const* d_in, const int* in_sizes, int n_in,
                              void* d_out, int out_size, void* d_ws, size_t ws_size,
                              hipStream_t stream) {
    const float* x     = (const float*)d_in[0];
    const float* Wq    = (const float*)d_in[1];
    const float* Wkv   = (const float*)d_in[2];
    const float* Wproj = (const float*)d_in[3];
    const float* bproj = (const float*)d_in[4];
    const float* gamma = (const float*)d_in[5];
    const float* beta  = (const float*)d_in[6];
    float* out = (float*)d_out;

    u16*   Wfrag  = (u16*)d_ws;                      // 1536*512 halves = 1.5 MiB
    u16*   Wpfrag = Wfrag + (size_t)1536 * 512;      // 512*512 halves = 0.5 MiB
    float* gkv    = (float*)(Wpfrag + (size_t)512 * 512);  // 2048 f32 = 8 KiB

    pack_wcat<<<1536, 64, 0, stream>>>(Wq, Wkv, gamma, Wfrag);
    pack_wp<<<512, 64, 0, stream>>>(Wproj, Wpfrag);
    gemv_g<<<32, 256, 0, stream>>>(Wkv, gamma, beta, gkv);

    fused_spa<<<4096 / NB, 1024, 0, stream>>>(x, Wfrag, Wpfrag, gkv, bproj, out);
}

// Round 13
// 588.441 us; speedup vs baseline: 1.2938x; 1.1593x over previous
//
#include <hip/hip_runtime.h>

typedef unsigned short u16;
typedef __attribute__((ext_vector_type(8))) short s8v;   // 8 x bf16
typedef __attribute__((ext_vector_type(4))) float f4v;   // 4 x f32

#define NB 4   // batches per block (weight L2 amortization)

__device__ __forceinline__ float bf2f(u16 u) {
    union { unsigned u; float f; } c; c.u = ((unsigned)u) << 16; return c.f;
}
__device__ __forceinline__ u16 f2bf(float f) {
    union { float f; unsigned u; } c; c.f = f;
    return (u16)((c.u + 0x7FFFu + ((c.u >> 16) & 1u)) >> 16);
}
__device__ __forceinline__ f4v mfma16(s8v a, s8v b, f4v c) {
    return __builtin_amdgcn_mfma_f32_16x16x32_bf16(a, b, c, 0, 0, 0);
}

__constant__ int POOL_A[12] = {2,5,1,0,8,14,11,10, 0,2,5,4};
__constant__ int POOL_B[12] = {3,6,4,7,9,15,12,13, 1,3,6,7};

// ---- prep: pack Wcat = [Wq_h | diag(g)Wk_h | diag(g)Wv_h] per head, fragment-major.
__global__ void pack_wcat(const float* __restrict__ Wq, const float* __restrict__ Wkv,
                          const float* __restrict__ gamma, u16* __restrict__ Wfrag) {
    int blk = blockIdx.x;               // (h*12+nt)*16+kt, 1536 blocks
    int kt = blk & 15, hn = blk >> 4;
    int nt = hn % 12, h = hn / 12;
    int lane = threadIdx.x, l15 = lane & 15, quad = lane >> 4;
    int r0 = kt * 32 + quad * 8;
    s8v v;
    if (nt < 4) {
        int c = h * 64 + nt * 16 + l15;
#pragma unroll
        for (int j = 0; j < 8; ++j) v[j] = (short)f2bf(Wq[(size_t)(r0 + j) * 512 + c]);
    } else {
        int c = (nt < 8) ? (h * 64 + (nt - 4) * 16 + l15)
                         : (512 + h * 64 + (nt - 8) * 16 + l15);
#pragma unroll
        for (int j = 0; j < 8; ++j)
            v[j] = (short)f2bf(gamma[r0 + j] * Wkv[(size_t)(r0 + j) * 1024 + c]);
    }
    *(s8v*)&Wfrag[(size_t)blk * 512 + lane * 8] = v;
}

__global__ void pack_wp(const float* __restrict__ Wproj, u16* __restrict__ Wpfrag) {
    int blk = blockIdx.x;               // 512 blocks
    int n = blk & 31, hk = blk >> 5;
    int kt = hk & 1, h = hk >> 1;
    int lane = threadIdx.x, l15 = lane & 15, quad = lane >> 4;
    int r0 = h * 64 + kt * 32 + quad * 8;
    int c = n * 16 + l15;
    s8v v;
#pragma unroll
    for (int j = 0; j < 8; ++j) v[j] = (short)f2bf(Wproj[(size_t)(r0 + j) * 512 + c]);
    *(s8v*)&Wpfrag[(size_t)blk * 512 + lane * 8] = v;
}

// gkv[h*256 + s*64 + c] — parallel: 32 blocks x 256 thr, r-split + LDS reduce
__global__ void gemv_g(const float* __restrict__ Wkv, const float* __restrict__ gamma,
                       const float* __restrict__ beta, float* __restrict__ gkv) {
    __shared__ float red[256];
    int o = blockIdx.x * 64 + (threadIdx.x & 63);   // output index 0..2047
    int rc = threadIdx.x >> 6;                      // r-chunk 0..3
    int h = o >> 8, s = (o >> 6) & 3, c = o & 63;
    int col = (s < 2) ? (h * 64 + c) : (512 + h * 64 + c);
    const float* vec = (s & 1) ? beta : gamma;
    float acc = 0.f;
    for (int r = rc * 128; r < rc * 128 + 128; ++r)
        acc += vec[r] * Wkv[(size_t)r * 1024 + col];
    red[threadIdx.x] = acc;
    __syncthreads();
    if (rc == 0)
        gkv[o] = red[threadIdx.x] + red[threadIdx.x + 64] +
                 red[threadIdx.x + 128] + red[threadIdx.x + 192];
}

// ---- fused kernel: EXACT round-2 structure (measured 396us, no spill) with two
// register-neutral LDS-geometry fixes:
//   VT stride 40->38 u16 (odd dword stride: scatter-write banks spread, ~free)
//   PB stride 32->40 (write/read bank spread)
// PV B-frag read switches to 4x ds_read_b32 (76B rows lose b128 alignment).
__global__ __launch_bounds__(1024, 4) void fused_spa(
    const float* __restrict__ x,
    const u16*  __restrict__ Wfrag,
    const u16*  __restrict__ Wpfrag,
    const float* __restrict__ gkv,
    const float* __restrict__ bproj,
    float* __restrict__ out)
{
    __shared__ __align__(16) unsigned char smem[162688];
    u16*   XS   = (u16*)smem;                   // [64][520]
    float* YS   = (float*)(smem + 66560);       // [64][132]  (k cols 0..63, v cols 64..127)
    u16*   QH   = (u16*)(smem + 100352);        // [64][72]
    u16*   OS   = (u16*)(smem + 109568);        // [64][72]
    u16*   KH   = (u16*)(smem + 118784);        // [128][72]
    u16*   VT   = (u16*)(smem + 137216);        // [4][64][38]  (odd-dword stride)
    u16*   PB   = (u16*)(smem + 156672);        // [4][16][40]
    float* STraw   = (float*)(smem + 161792);   // [64][2] (mu, E[x^2]) -- dead after P2b
    float* STcross = (float*)(smem + 162304);   // [48]                 -- dead after P2b
    float* STfin   = (float*)(smem + 161792);   // [112][2] overlays STraw/STcross

    const int tid  = (int)threadIdx.x;
    const int w    = tid >> 6;                  // 0..15
    const int lane = tid & 63;
    const int l15  = lane & 15;
    const int quad = lane >> 4;
    const size_t grow0 = (size_t)blockIdx.x * (NB * 16);
    const int abatch = w - 12;                  // attn-wave batch (valid for w>=12)

    // P1: stage x (f32) -> XS bf16. row=tid>>4 (0..63), 32 cols each
    {
        int row = tid >> 4, col = (tid & 15) * 32;
        const float4* src = (const float4*)(x + (grow0 + row) * 512 + col);
        u16* dst = XS + row * 520 + col;
#pragma unroll
        for (int i = 0; i < 4; ++i) {
            float4 f0 = src[2 * i], f1 = src[2 * i + 1];
            s8v o;
            o[0] = (short)f2bf(f0.x); o[1] = (short)f2bf(f0.y);
            o[2] = (short)f2bf(f0.z); o[3] = (short)f2bf(f0.w);
            o[4] = (short)f2bf(f1.x); o[5] = (short)f2bf(f1.y);
            o[6] = (short)f2bf(f1.z); o[7] = (short)f2bf(f1.w);
            *(s8v*)(dst + i * 8) = o;
        }
    }
    __syncthreads();

    // P2a: per-row stats + cross dots
    {
#pragma unroll
        for (int i = 0; i < 4; ++i) {
            int row = w * 4 + i;                  // 0..63
            s8v t = *(const s8v*)&XS[row * 520 + lane * 8];
            float s = 0.f, s2 = 0.f;
#pragma unroll
            for (int j = 0; j < 8; ++j) { float v = bf2f((u16)t[j]); s += v; s2 += v * v; }
#pragma unroll
            for (int d = 1; d < 64; d <<= 1) { s += __shfl_xor(s, d); s2 += __shfl_xor(s2, d); }
            if (lane == 0) { STraw[row * 2] = s * (1.f/512.f); STraw[row * 2 + 1] = s2 * (1.f/512.f); }
        }
#pragma unroll
        for (int i = 0; i < 3; ++i) {
            int d = w * 3 + i;                    // 0..47
            int batch = d / 12, pr = d % 12;
            int ra = batch * 16 + POOL_A[pr], rb = batch * 16 + POOL_B[pr];
            s8v ta = *(const s8v*)&XS[ra * 520 + lane * 8];
            s8v tb = *(const s8v*)&XS[rb * 520 + lane * 8];
            float s = 0.f;
#pragma unroll
            for (int j = 0; j < 8; ++j) s += bf2f((u16)ta[j]) * bf2f((u16)tb[j]);
#pragma unroll
            for (int dd = 1; dd < 64; dd <<= 1) s += __shfl_xor(s, dd);
            if (lane == 0) STcross[batch * 12 + pr] = s * (1.f/512.f);
        }
    }
    __syncthreads();

    // P2b: finalize (rstd, -rstd*mu). STfin overlays -> regs, barrier, write.
    {
        float f_rstd = 0.f, f_nmu = 0.f;
        if (tid < 112) {
            int batch = tid / 28, pr = tid % 28;
            float mu, E2;
            if (pr < 16) {
                mu = STraw[(batch * 16 + pr) * 2];
                E2 = STraw[(batch * 16 + pr) * 2 + 1];
            } else {
                int j = pr - 16;
                int ra = batch * 16 + POOL_A[j], rb = batch * 16 + POOL_B[j];
                float ma = STraw[ra * 2], mb = STraw[rb * 2];
                float Ea = STraw[ra * 2 + 1], Eb = STraw[rb * 2 + 1];
                mu = 0.5f * (ma + mb);
                E2 = 0.25f * (Ea + 2.f * STcross[batch * 12 + j] + Eb);
            }
            float var = E2 - mu * mu;
            f_rstd = rsqrtf(var + 1e-5f);
            f_nmu  = -f_rstd * mu;
        }
        __syncthreads();
        if (tid < 112) { STfin[tid * 2] = f_rstd; STfin[tid * 2 + 1] = f_nmu; }
        __syncthreads();
    }

    f4v psum[8] = {};          // proj acc: tiles m=0..3 x nn=0..1 (cols n = w*2+nn)
    s8v aq0 = {}, aq1 = {};    // attn-wave q fragments (preloaded in phase B)

    for (int h = 0; h <= 8; ++h) {
        // ---------------- Phase A ----------------
        if (h < 8 && w < 12) {
            // GEMM(h): wave = nt, 4 M-tiles each, B-frags from L2
            f4v acc[4] = {};
            const u16* bp = Wfrag + ((size_t)(h * 12 + w) * 16) * 512 + lane * 8;
            for (int kt = 0; kt < 16; ++kt) {
                s8v bb = *(const s8v*)(bp + kt * 512);
                int ka = kt * 32 + quad * 8;
#pragma unroll
                for (int m = 0; m < 4; ++m) {
                    s8v a = *(const s8v*)&XS[(m * 16 + l15) * 520 + ka];
                    acc[m] = mfma16(a, bb, acc[m]);
                }
            }
            if (w < 4) {            // q (scaled by 1/8)
#pragma unroll
                for (int m = 0; m < 4; ++m)
#pragma unroll
                    for (int r = 0; r < 4; ++r)
                        QH[(m * 16 + quad * 4 + r) * 72 + w * 16 + l15] = f2bf(acc[m][r] * 0.125f);
            } else if (w < 8) {     // raw Yk (f32)
#pragma unroll
                for (int m = 0; m < 4; ++m)
#pragma unroll
                    for (int r = 0; r < 4; ++r)
                        YS[(m * 16 + quad * 4 + r) * 132 + (w - 4) * 16 + l15] = acc[m][r];
            } else {                // raw Yv (f32)
#pragma unroll
                for (int m = 0; m < 4; ++m)
#pragma unroll
                    for (int r = 0; r < 4; ++r)
                        YS[(m * 16 + quad * 4 + r) * 132 + 64 + (w - 8) * 16 + l15] = acc[m][r];
            }
        } else if (h >= 1 && w >= 12) {
            // Attention(h-1), batch = abatch. q in regs; K/V from (h-1) buffers.
            f4v s0 = {}, s1 = {};
            {
                s8v bk0 = *(const s8v*)&KH[(abatch * 32 + l15) * 72 + quad * 8];
                s8v bk1 = *(const s8v*)&KH[(abatch * 32 + 16 + l15) * 72 + quad * 8];
                s0 = mfma16(aq0, bk0, s0);
                s1 = mfma16(aq0, bk1, s1);
                bk0 = *(const s8v*)&KH[(abatch * 32 + l15) * 72 + 32 + quad * 8];
                bk1 = *(const s8v*)&KH[(abatch * 32 + 16 + l15) * 72 + 32 + quad * 8];
                s0 = mfma16(aq1, bk0, s0);
                s1 = mfma16(aq1, bk1, s1);
            }
            bool valid1 = (l15 < 12);
#pragma unroll
            for (int r = 0; r < 4; ++r) {
                float v0 = s0[r];
                float v1 = valid1 ? s1[r] : -1e30f;
                float mx = fmaxf(v0, v1);
#pragma unroll
                for (int d = 1; d < 16; d <<= 1) mx = fmaxf(mx, __shfl_xor(mx, d));
                float p0 = __expf(v0 - mx);
                float p1 = valid1 ? __expf(v1 - mx) : 0.f;
                float sm = p0 + p1;
#pragma unroll
                for (int d = 1; d < 16; d <<= 1) sm += __shfl_xor(sm, d);
                float inv = 1.f / sm;
                int row = quad * 4 + r;
                PB[(abatch * 16 + row) * 40 + l15]      = f2bf(p0 * inv);
                PB[(abatch * 16 + row) * 40 + 16 + l15] = f2bf(p1 * inv);
            }
            // PV (same wave reads its own P writes; compiler inserts lgkm waits)
            s8v ap = *(const s8v*)&PB[(abatch * 16 + l15) * 40 + quad * 8];
            const unsigned* vtw = (const unsigned*)VT;
#pragma unroll
            for (int nt = 0; nt < 4; ++nt) {
                int base = (abatch * 64 + nt * 16 + l15) * 19 + quad * 4;  // dword index
                union { unsigned u[4]; s8v v; } cv;
                cv.u[0] = vtw[base];     cv.u[1] = vtw[base + 1];
                cv.u[2] = vtw[base + 2]; cv.u[3] = vtw[base + 3];
                f4v o = {};
                o = mfma16(ap, cv.v, o);
#pragma unroll
                for (int r = 0; r < 4; ++r)
                    OS[(abatch * 16 + quad * 4 + r) * 72 + nt * 16 + l15] = f2bf(o[r]);
            }
        }
        __syncthreads();

        // ---------------- Phase B ----------------
        if (h >= 1) {
            // proj(h-1): all 16 waves, cols n = w*2 + {0,1}, K-slice = head h-1
            const int hp = h - 1;
#pragma unroll
            for (int kt = 0; kt < 2; ++kt) {
                int ka = kt * 32 + quad * 8;
                s8v a[4];
#pragma unroll
                for (int m = 0; m < 4; ++m)
                    a[m] = *(const s8v*)&OS[(m * 16 + l15) * 72 + ka];
#pragma unroll
                for (int nn = 0; nn < 2; ++nn) {
                    int n = w * 2 + nn;
                    s8v bb = *(const s8v*)&Wpfrag[((size_t)((hp * 2 + kt) * 32 + n)) * 512 + lane * 8];
#pragma unroll
                    for (int m = 0; m < 4; ++m)
                        psum[m * 2 + nn] = mfma16(a[m], bb, psum[m * 2 + nn]);
                }
            }
        }
        if (h < 8) {
            // P3b(h): form k (KH) and v-transposed (VT) from raw Y via per-row affine
            // (round-2 combined single pass -- no extra register pressure)
            {
                int rowid = tid >> 3;             // 0..127
                int c0 = (tid & 7) * 8;           // 0..56
                int batch = rowid >> 5, pr = rowid & 31;
                if (pr < 28) {
                    float alpha = STfin[(batch * 28 + pr) * 2];
                    float beta_ = STfin[(batch * 28 + pr) * 2 + 1];
                    float yk[8], yv[8];
                    if (pr < 16) {
                        const float* yr = YS + (batch * 16 + pr) * 132;
#pragma unroll
                        for (int i = 0; i < 8; ++i) { yk[i] = yr[c0 + i]; yv[i] = yr[64 + c0 + i]; }
                    } else {
                        int j = pr - 16;
                        const float* ya = YS + (batch * 16 + POOL_A[j]) * 132;
                        const float* yb = YS + (batch * 16 + POOL_B[j]) * 132;
#pragma unroll
                        for (int i = 0; i < 8; ++i) {
                            yk[i] = 0.5f * (ya[c0 + i] + yb[c0 + i]);
                            yv[i] = 0.5f * (ya[64 + c0 + i] + yb[64 + c0 + i]);
                        }
                    }
                    const float* g = gkv + h * 256;
                    s8v kk;
#pragma unroll
                    for (int i = 0; i < 8; ++i) {
                        float kf = alpha * yk[i] + beta_ * g[c0 + i]       + g[64 + c0 + i];
                        float vf = alpha * yv[i] + beta_ * g[128 + c0 + i] + g[192 + c0 + i];
                        kk[i] = (short)f2bf(kf);
                        VT[(batch * 64 + c0 + i) * 38 + pr] = f2bf(vf);
                    }
                    *(s8v*)&KH[(batch * 32 + pr) * 72 + c0] = kk;
                } else {
                    s8v z = {0,0,0,0,0,0,0,0};
                    *(s8v*)&KH[(batch * 32 + pr) * 72 + c0] = z;
#pragma unroll
                    for (int i = 0; i < 8; ++i) VT[(batch * 64 + c0 + i) * 38 + pr] = 0;
                }
            }
            // attn waves: preload q(h) fragments (QH stable until GEMM(h+1))
            if (w >= 12) {
                aq0 = *(const s8v*)&QH[(abatch * 16 + l15) * 72 + quad * 8];
                aq1 = *(const s8v*)&QH[(abatch * 16 + l15) * 72 + 32 + quad * 8];
            }
        }
        __syncthreads();
    }

    // P4: write out (f32) + bias
#pragma unroll
    for (int nn = 0; nn < 2; ++nn) {
        int n = w * 2 + nn;
        float bias = bproj[n * 16 + l15];
#pragma unroll
        for (int m = 0; m < 4; ++m)
#pragma unroll
            for (int r = 0; r < 4; ++r)
                out[(grow0 + m * 16 + quad * 4 + r) * 512 + n * 16 + l15] =
                    psum[m * 2 + nn][r] + bias;
    }
}

extern "C" void kernel_launch(void* const* d_in, const int* in_sizes, int n_in,
                              void* d_out, int out_size, void* d_ws, size_t ws_size,
                              hipStream_t stream) {
    const float* x     = (const float*)d_in[0];
    const float* Wq    = (const float*)d_in[1];
    const float* Wkv   = (const float*)d_in[2];
    const float* Wproj = (const float*)d_in[3];
    const float* bproj = (const float*)d_in[4];
    const float* gamma = (const float*)d_in[5];
    const float* beta  = (const float*)d_in[6];
    float* out = (float*)d_out;

    u16*   Wfrag  = (u16*)d_ws;                      // 1536*512 halves = 1.5 MiB
    u16*   Wpfrag = Wfrag + (size_t)1536 * 512;      // 512*512 halves = 0.5 MiB
    float* gkv    = (float*)(Wpfrag + (size_t)512 * 512);  // 2048 f32 = 8 KiB

    pack_wcat<<<1536, 64, 0, stream>>>(Wq, Wkv, gamma, Wfrag);
    pack_wp<<<512, 64, 0, stream>>>(Wproj, Wpfrag);
    gemv_g<<<32, 256, 0, stream>>>(Wkv, gamma, beta, gkv);

    fused_spa<<<4096 / NB, 1024, 0, stream>>>(x, Wfrag, Wpfrag, gkv, bproj, out);
}

// Round 14
// 576.733 us; speedup vs baseline: 1.3201x; 1.0203x over previous
//
#include <hip/hip_runtime.h>

typedef unsigned short u16;
typedef __attribute__((ext_vector_type(8))) short s8v;   // 8 x bf16
typedef __attribute__((ext_vector_type(4))) float f4v;   // 4 x f32

#define NB 4   // batches per block (weight L2 amortization)

__device__ __forceinline__ float bf2f(u16 u) {
    union { unsigned u; float f; } c; c.u = ((unsigned)u) << 16; return c.f;
}
__device__ __forceinline__ u16 f2bf(float f) {
    union { float f; unsigned u; } c; c.f = f;
    return (u16)((c.u + 0x7FFFu + ((c.u >> 16) & 1u)) >> 16);
}
__device__ __forceinline__ f4v mfma16(s8v a, s8v b, f4v c) {
    return __builtin_amdgcn_mfma_f32_16x16x32_bf16(a, b, c, 0, 0, 0);
}

__constant__ int POOL_A[12] = {2,5,1,0,8,14,11,10, 0,2,5,4};
__constant__ int POOL_B[12] = {3,6,4,7,9,15,12,13, 1,3,6,7};

// ---- prep: pack Wcat = [Wq_h | diag(g)Wk_h | diag(g)Wv_h] per head, fragment-major.
__global__ void pack_wcat(const float* __restrict__ Wq, const float* __restrict__ Wkv,
                          const float* __restrict__ gamma, u16* __restrict__ Wfrag) {
    int blk = blockIdx.x;               // (h*12+nt)*16+kt, 1536 blocks
    int kt = blk & 15, hn = blk >> 4;
    int nt = hn % 12, h = hn / 12;
    int lane = threadIdx.x, l15 = lane & 15, quad = lane >> 4;
    int r0 = kt * 32 + quad * 8;
    s8v v;
    if (nt < 4) {
        int c = h * 64 + nt * 16 + l15;
#pragma unroll
        for (int j = 0; j < 8; ++j) v[j] = (short)f2bf(Wq[(size_t)(r0 + j) * 512 + c]);
    } else {
        int c = (nt < 8) ? (h * 64 + (nt - 4) * 16 + l15)
                         : (512 + h * 64 + (nt - 8) * 16 + l15);
#pragma unroll
        for (int j = 0; j < 8; ++j)
            v[j] = (short)f2bf(gamma[r0 + j] * Wkv[(size_t)(r0 + j) * 1024 + c]);
    }
    *(s8v*)&Wfrag[(size_t)blk * 512 + lane * 8] = v;
}

__global__ void pack_wp(const float* __restrict__ Wproj, u16* __restrict__ Wpfrag) {
    int blk = blockIdx.x;               // 512 blocks
    int n = blk & 31, hk = blk >> 5;
    int kt = hk & 1, h = hk >> 1;
    int lane = threadIdx.x, l15 = lane & 15, quad = lane >> 4;
    int r0 = h * 64 + kt * 32 + quad * 8;
    int c = n * 16 + l15;
    s8v v;
#pragma unroll
    for (int j = 0; j < 8; ++j) v[j] = (short)f2bf(Wproj[(size_t)(r0 + j) * 512 + c]);
    *(s8v*)&Wpfrag[(size_t)blk * 512 + lane * 8] = v;
}

// gkv[h*256 + s*64 + c] — parallel: 32 blocks x 256 thr, r-split + LDS reduce
__global__ void gemv_g(const float* __restrict__ Wkv, const float* __restrict__ gamma,
                       const float* __restrict__ beta, float* __restrict__ gkv) {
    __shared__ float red[256];
    int o = blockIdx.x * 64 + (threadIdx.x & 63);   // output index 0..2047
    int rc = threadIdx.x >> 6;                      // r-chunk 0..3
    int h = o >> 8, s = (o >> 6) & 3, c = o & 63;
    int col = (s < 2) ? (h * 64 + c) : (512 + h * 64 + c);
    const float* vec = (s & 1) ? beta : gamma;
    float acc = 0.f;
    for (int r = rc * 128; r < rc * 128 + 128; ++r)
        acc += vec[r] * Wkv[(size_t)r * 1024 + col];
    red[threadIdx.x] = acc;
    __syncthreads();
    if (rc == 0)
        gkv[o] = red[threadIdx.x] + red[threadIdx.x + 64] +
                 red[threadIdx.x + 128] + red[threadIdx.x + 192];
}

// ---- fused kernel: R13 base (combined P3b, VT stride 38, PB stride 40 — 403us,
// spill-free) + R6's 2-stream x 2-M GEMM (halves XS A-fragment LDS traffic,
// the measured phase-A floor: 768 -> 384 b128 reads/CU/head).
// Deconfounded: R10/R13 proved the earlier spill came from split-P3b, not this GEMM.
__global__ __launch_bounds__(1024, 4) void fused_spa(
    const float* __restrict__ x,
    const u16*  __restrict__ Wfrag,
    const u16*  __restrict__ Wpfrag,
    const float* __restrict__ gkv,
    const float* __restrict__ bproj,
    float* __restrict__ out)
{
    __shared__ __align__(16) unsigned char smem[162688];
    u16*   XS   = (u16*)smem;                   // [64][520]
    float* YS   = (float*)(smem + 66560);       // [64][132]  (k cols 0..63, v cols 64..127)
    u16*   QH   = (u16*)(smem + 100352);        // [64][72]
    u16*   OS   = (u16*)(smem + 109568);        // [64][72]
    u16*   KH   = (u16*)(smem + 118784);        // [128][72]
    u16*   VT   = (u16*)(smem + 137216);        // [4][64][38]  (odd-dword stride)
    u16*   PB   = (u16*)(smem + 156672);        // [4][16][40]
    float* STraw   = (float*)(smem + 161792);   // [64][2] (mu, E[x^2]) -- dead after P2b
    float* STcross = (float*)(smem + 162304);   // [48]                 -- dead after P2b
    float* STfin   = (float*)(smem + 161792);   // [112][2] overlays STraw/STcross

    const int tid  = (int)threadIdx.x;
    const int w    = tid >> 6;                  // 0..15
    const int lane = tid & 63;
    const int l15  = lane & 15;
    const int quad = lane >> 4;
    const size_t grow0 = (size_t)blockIdx.x * (NB * 16);
    const int abatch = w - 12;                  // attn-wave batch (valid for w>=12)

    // P1: stage x (f32) -> XS bf16. row=tid>>4 (0..63), 32 cols each
    {
        int row = tid >> 4, col = (tid & 15) * 32;
        const float4* src = (const float4*)(x + (grow0 + row) * 512 + col);
        u16* dst = XS + row * 520 + col;
#pragma unroll
        for (int i = 0; i < 4; ++i) {
            float4 f0 = src[2 * i], f1 = src[2 * i + 1];
            s8v o;
            o[0] = (short)f2bf(f0.x); o[1] = (short)f2bf(f0.y);
            o[2] = (short)f2bf(f0.z); o[3] = (short)f2bf(f0.w);
            o[4] = (short)f2bf(f1.x); o[5] = (short)f2bf(f1.y);
            o[6] = (short)f2bf(f1.z); o[7] = (short)f2bf(f1.w);
            *(s8v*)(dst + i * 8) = o;
        }
    }
    __syncthreads();

    // P2a: per-row stats + cross dots
    {
#pragma unroll
        for (int i = 0; i < 4; ++i) {
            int row = w * 4 + i;                  // 0..63
            s8v t = *(const s8v*)&XS[row * 520 + lane * 8];
            float s = 0.f, s2 = 0.f;
#pragma unroll
            for (int j = 0; j < 8; ++j) { float v = bf2f((u16)t[j]); s += v; s2 += v * v; }
#pragma unroll
            for (int d = 1; d < 64; d <<= 1) { s += __shfl_xor(s, d); s2 += __shfl_xor(s2, d); }
            if (lane == 0) { STraw[row * 2] = s * (1.f/512.f); STraw[row * 2 + 1] = s2 * (1.f/512.f); }
        }
#pragma unroll
        for (int i = 0; i < 3; ++i) {
            int d = w * 3 + i;                    // 0..47
            int batch = d / 12, pr = d % 12;
            int ra = batch * 16 + POOL_A[pr], rb = batch * 16 + POOL_B[pr];
            s8v ta = *(const s8v*)&XS[ra * 520 + lane * 8];
            s8v tb = *(const s8v*)&XS[rb * 520 + lane * 8];
            float s = 0.f;
#pragma unroll
            for (int j = 0; j < 8; ++j) s += bf2f((u16)ta[j]) * bf2f((u16)tb[j]);
#pragma unroll
            for (int dd = 1; dd < 64; dd <<= 1) s += __shfl_xor(s, dd);
            if (lane == 0) STcross[batch * 12 + pr] = s * (1.f/512.f);
        }
    }
    __syncthreads();

    // P2b: finalize (rstd, -rstd*mu). STfin overlays -> regs, barrier, write.
    {
        float f_rstd = 0.f, f_nmu = 0.f;
        if (tid < 112) {
            int batch = tid / 28, pr = tid % 28;
            float mu, E2;
            if (pr < 16) {
                mu = STraw[(batch * 16 + pr) * 2];
                E2 = STraw[(batch * 16 + pr) * 2 + 1];
            } else {
                int j = pr - 16;
                int ra = batch * 16 + POOL_A[j], rb = batch * 16 + POOL_B[j];
                float ma = STraw[ra * 2], mb = STraw[rb * 2];
                float Ea = STraw[ra * 2 + 1], Eb = STraw[rb * 2 + 1];
                mu = 0.5f * (ma + mb);
                E2 = 0.25f * (Ea + 2.f * STcross[batch * 12 + j] + Eb);
            }
            float var = E2 - mu * mu;
            f_rstd = rsqrtf(var + 1e-5f);
            f_nmu  = -f_rstd * mu;
        }
        __syncthreads();
        if (tid < 112) { STfin[tid * 2] = f_rstd; STfin[tid * 2 + 1] = f_nmu; }
        __syncthreads();
    }

    f4v psum[8] = {};          // proj acc: tiles m=0..3 x nn=0..1 (cols n = w*2+nn)
    s8v aq0 = {}, aq1 = {};    // attn-wave q fragments (preloaded in phase B)

    for (int h = 0; h <= 8; ++h) {
        // ---------------- Phase A ----------------
        if (h < 8 && w < 12) {
            // GEMM(h): wave = (np = w>>1, mp = w&1). 2 nt-streams x 2 M-tiles.
            // np<4: (q_np, k_np) = nt {np, 4+np}; np=4: v{8,9}; np=5: v{10,11}.
            // One A-read feeds 2 MFMAs (halves XS LDS traffic); 12 waves = 3/SIMD.
            int np = w >> 1, mp = w & 1;
            int nt0 = (np < 4) ? np : (8 + (np - 4) * 2);
            int nt1 = (np < 4) ? (4 + np) : (9 + (np - 4) * 2);
            f4v acc0[2] = {}, acc1[2] = {};
            const u16* bp0 = Wfrag + ((size_t)(h * 12 + nt0) * 16) * 512 + lane * 8;
            const u16* bp1 = Wfrag + ((size_t)(h * 12 + nt1) * 16) * 512 + lane * 8;
#pragma unroll 2
            for (int kt = 0; kt < 16; ++kt) {
                s8v b0 = *(const s8v*)(bp0 + kt * 512);
                s8v b1 = *(const s8v*)(bp1 + kt * 512);
                int ka = kt * 32 + quad * 8;
#pragma unroll
                for (int mm = 0; mm < 2; ++mm) {
                    s8v a = *(const s8v*)&XS[((mp * 2 + mm) * 16 + l15) * 520 + ka];
                    acc0[mm] = mfma16(a, b0, acc0[mm]);
                    acc1[mm] = mfma16(a, b1, acc1[mm]);
                }
            }
            if (np < 4) {
#pragma unroll
                for (int mm = 0; mm < 2; ++mm)
#pragma unroll
                    for (int r = 0; r < 4; ++r) {
                        int row = (mp * 2 + mm) * 16 + quad * 4 + r;
                        QH[row * 72 + np * 16 + l15] = f2bf(acc0[mm][r] * 0.125f);  // q (scaled)
                        YS[row * 132 + np * 16 + l15] = acc1[mm][r];                // raw Yk
                    }
            } else {
                int v0 = (np - 4) * 2;
#pragma unroll
                for (int mm = 0; mm < 2; ++mm)
#pragma unroll
                    for (int r = 0; r < 4; ++r) {
                        int row = (mp * 2 + mm) * 16 + quad * 4 + r;
                        YS[row * 132 + 64 + v0 * 16 + l15]       = acc0[mm][r];     // raw Yv
                        YS[row * 132 + 64 + (v0 + 1) * 16 + l15] = acc1[mm][r];     // raw Yv
                    }
            }
        } else if (h >= 1 && w >= 12) {
            // Attention(h-1), batch = abatch. q in regs; K/V from (h-1) buffers.
            f4v s0 = {}, s1 = {};
            {
                s8v bk0 = *(const s8v*)&KH[(abatch * 32 + l15) * 72 + quad * 8];
                s8v bk1 = *(const s8v*)&KH[(abatch * 32 + 16 + l15) * 72 + quad * 8];
                s0 = mfma16(aq0, bk0, s0);
                s1 = mfma16(aq0, bk1, s1);
                bk0 = *(const s8v*)&KH[(abatch * 32 + l15) * 72 + 32 + quad * 8];
                bk1 = *(const s8v*)&KH[(abatch * 32 + 16 + l15) * 72 + 32 + quad * 8];
                s0 = mfma16(aq1, bk0, s0);
                s1 = mfma16(aq1, bk1, s1);
            }
            bool valid1 = (l15 < 12);
#pragma unroll
            for (int r = 0; r < 4; ++r) {
                float v0 = s0[r];
                float v1 = valid1 ? s1[r] : -1e30f;
                float mx = fmaxf(v0, v1);
#pragma unroll
                for (int d = 1; d < 16; d <<= 1) mx = fmaxf(mx, __shfl_xor(mx, d));
                float p0 = __expf(v0 - mx);
                float p1 = valid1 ? __expf(v1 - mx) : 0.f;
                float sm = p0 + p1;
#pragma unroll
                for (int d = 1; d < 16; d <<= 1) sm += __shfl_xor(sm, d);
                float inv = 1.f / sm;
                int row = quad * 4 + r;
                PB[(abatch * 16 + row) * 40 + l15]      = f2bf(p0 * inv);
                PB[(abatch * 16 + row) * 40 + 16 + l15] = f2bf(p1 * inv);
            }
            // PV (same wave reads its own P writes; compiler inserts lgkm waits)
            s8v ap = *(const s8v*)&PB[(abatch * 16 + l15) * 40 + quad * 8];
            const unsigned* vtw = (const unsigned*)VT;
#pragma unroll
            for (int nt = 0; nt < 4; ++nt) {
                int base = (abatch * 64 + nt * 16 + l15) * 19 + quad * 4;  // dword index
                union { unsigned u[4]; s8v v; } cv;
                cv.u[0] = vtw[base];     cv.u[1] = vtw[base + 1];
                cv.u[2] = vtw[base + 2]; cv.u[3] = vtw[base + 3];
                f4v o = {};
                o = mfma16(ap, cv.v, o);
#pragma unroll
                for (int r = 0; r < 4; ++r)
                    OS[(abatch * 16 + quad * 4 + r) * 72 + nt * 16 + l15] = f2bf(o[r]);
            }
        }
        __syncthreads();

        // ---------------- Phase B ----------------
        if (h >= 1) {
            // proj(h-1): all 16 waves, cols n = w*2 + {0,1}, K-slice = head h-1
            const int hp = h - 1;
#pragma unroll
            for (int kt = 0; kt < 2; ++kt) {
                int ka = kt * 32 + quad * 8;
                s8v a[4];
#pragma unroll
                for (int m = 0; m < 4; ++m)
                    a[m] = *(const s8v*)&OS[(m * 16 + l15) * 72 + ka];
#pragma unroll
                for (int nn = 0; nn < 2; ++nn) {
                    int n = w * 2 + nn;
                    s8v bb = *(const s8v*)&Wpfrag[((size_t)((hp * 2 + kt) * 32 + n)) * 512 + lane * 8];
#pragma unroll
                    for (int m = 0; m < 4; ++m)
                        psum[m * 2 + nn] = mfma16(a[m], bb, psum[m * 2 + nn]);
                }
            }
        }
        if (h < 8) {
            // P3b(h): form k (KH) and v-transposed (VT) from raw Y via per-row affine
            // (combined single pass -- spill-free register profile, verified R13)
            {
                int rowid = tid >> 3;             // 0..127
                int c0 = (tid & 7) * 8;           // 0..56
                int batch = rowid >> 5, pr = rowid & 31;
                if (pr < 28) {
                    float alpha = STfin[(batch * 28 + pr) * 2];
                    float beta_ = STfin[(batch * 28 + pr) * 2 + 1];
                    float yk[8], yv[8];
                    if (pr < 16) {
                        const float* yr = YS + (batch * 16 + pr) * 132;
#pragma unroll
                        for (int i = 0; i < 8; ++i) { yk[i] = yr[c0 + i]; yv[i] = yr[64 + c0 + i]; }
                    } else {
                        int j = pr - 16;
                        const float* ya = YS + (batch * 16 + POOL_A[j]) * 132;
                        const float* yb = YS + (batch * 16 + POOL_B[j]) * 132;
#pragma unroll
                        for (int i = 0; i < 8; ++i) {
                            yk[i] = 0.5f * (ya[c0 + i] + yb[c0 + i]);
                            yv[i] = 0.5f * (ya[64 + c0 + i] + yb[64 + c0 + i]);
                        }
                    }
                    const float* g = gkv + h * 256;
                    s8v kk;
#pragma unroll
                    for (int i = 0; i < 8; ++i) {
                        float kf = alpha * yk[i] + beta_ * g[c0 + i]       + g[64 + c0 + i];
                        float vf = alpha * yv[i] + beta_ * g[128 + c0 + i] + g[192 + c0 + i];
                        kk[i] = (short)f2bf(kf);
                        VT[(batch * 64 + c0 + i) * 38 + pr] = f2bf(vf);
                    }
                    *(s8v*)&KH[(batch * 32 + pr) * 72 + c0] = kk;
                } else {
                    s8v z = {0,0,0,0,0,0,0,0};
                    *(s8v*)&KH[(batch * 32 + pr) * 72 + c0] = z;
#pragma unroll
                    for (int i = 0; i < 8; ++i) VT[(batch * 64 + c0 + i) * 38 + pr] = 0;
                }
            }
            // attn waves: preload q(h) fragments (QH stable until GEMM(h+1))
            if (w >= 12) {
                aq0 = *(const s8v*)&QH[(abatch * 16 + l15) * 72 + quad * 8];
                aq1 = *(const s8v*)&QH[(abatch * 16 + l15) * 72 + 32 + quad * 8];
            }
        }
        __syncthreads();
    }

    // P4: write out (f32) + bias
#pragma unroll
    for (int nn = 0; nn < 2; ++nn) {
        int n = w * 2 + nn;
        float bias = bproj[n * 16 + l15];
#pragma unroll
        for (int m = 0; m < 4; ++m)
#pragma unroll
            for (int r = 0; r < 4; ++r)
                out[(grow0 + m * 16 + quad * 4 + r) * 512 + n * 16 + l15] =
                    psum[m * 2 + nn][r] + bias;
    }
}

extern "C" void kernel_launch(void* const* d_in, const int* in_sizes, int n_in,
                              void* d_out, int out_size, void* d_ws, size_t ws_size,
                              hipStream_t stream) {
    const float* x     = (const float*)d_in[0];
    const float* Wq    = (const float*)d_in[1];
    const float* Wkv   = (const float*)d_in[2];
    const float* Wproj = (const float*)d_in[3];
    const float* bproj = (const float*)d_in[4];
    const float* gamma = (const float*)d_in[5];
    const float* beta  = (const float*)d_in[6];
    float* out = (float*)d_out;

    u16*   Wfrag  = (u16*)d_ws;                      // 1536*512 halves = 1.5 MiB
    u16*   Wpfrag = Wfrag + (size_t)1536 * 512;      // 512*512 halves = 0.5 MiB
    float* gkv    = (float*)(Wpfrag + (size_t)512 * 512);  // 2048 f32 = 8 KiB

    pack_wcat<<<1536, 64, 0, stream>>>(Wq, Wkv, gamma, Wfrag);
    pack_wp<<<512, 64, 0, stream>>>(Wproj, Wpfrag);
    gemv_g<<<32, 256, 0, stream>>>(Wkv, gamma, beta, gkv);

    fused_spa<<<4096 / NB, 1024, 0, stream>>>(x, Wfrag, Wpfrag, gkv, bproj, out);
}